// Round 7
// baseline (271.342 us; speedup 1.0000x reference)
//
#include <hip/hip_runtime.h>
#include <hip/hip_bf16.h>
#include <math.h>

// Problem constants
#define BB   2
#define CM   192        // D_MODEL
#define DI   384        // D_INNER
#define LL   16384      // D*H*W
#define NST  16         // D_STATE
#define RDT  12         // DT_RANK
#define XJ   44         // DT_RANK + 2*D_STATE
#define NC   512        // scan chunks
#define CLEN 32         // chunk length (NC*CLEN == LL)
#define NCH  (NC / 16)  // chunks per combine-thread
#define DBS  64         // dblT row stride (GEMM2 padded M)
#define XZS  768        // xzT row stride
#define CVT  32         // conv t-tile
#define DTT  32         // dt t-tile

typedef __attribute__((ext_vector_type(8))) short bf16x8;
typedef __attribute__((ext_vector_type(4))) float f32x4;
typedef unsigned short ushort_t;

static __device__ __forceinline__ ushort_t f2bf(float f) {
  __hip_bfloat16 h = __float2bfloat16(f);
  return *reinterpret_cast<ushort_t*>(&h);
}
static __device__ __forceinline__ float bf2f(ushort_t u) {
  __hip_bfloat16 h;
  *reinterpret_cast<ushort_t*>(&h) = u;
  return __bfloat162float(h);
}

// ---------------------------------------------------------------------------
// PW = proj_w(192x192) @ out_proj_w(192x384)   (fp32, tiny)
__global__ __launch_bounds__(256) void fuse_proj_kernel(
    const float* __restrict__ pw, const float* __restrict__ ow, float* __restrict__ PW) {
  int idx = blockIdx.x * 256 + threadIdx.x;
  if (idx >= CM * DI) return;
  int o = idx / DI, d = idx % DI;
  float s = 0.f;
  #pragma unroll 4
  for (int c = 0; c < CM; c++) s += pw[o * CM + c] * ow[c * DI + d];
  PW[idx] = s;
}

// ---------------------------------------------------------------------------
// Weight conversions to bf16 (x_proj padded 44 -> 64 rows with zeros)
__global__ __launch_bounds__(256) void cvt_weights_kernel(
    const float* __restrict__ ipw, const float* __restrict__ xpw,
    const float* __restrict__ PW,
    ushort_t* __restrict__ ipw_bf, ushort_t* __restrict__ xpw_bf,
    ushort_t* __restrict__ PW_bf) {
  int i = blockIdx.x * 256 + threadIdx.x;
  if (i < 2 * DI * CM) ipw_bf[i] = f2bf(ipw[i]);          // 768x192
  if (i < DBS * DI) {                                      // 64x384 (pad)
    int r = i / DI;
    xpw_bf[i] = (r < XJ) ? f2bf(xpw[i]) : (ushort_t)0;
  }
  if (i < CM * DI) PW_bf[i] = f2bf(PW[i]);                 // 192x384
}

// ---------------------------------------------------------------------------
// per-(b,c) mean / rstd over L
__global__ __launch_bounds__(256) void norm_stats_kernel(
    const float* __restrict__ x, float* __restrict__ mu, float* __restrict__ rstd) {
  int bc = blockIdx.x;
  const float* p = x + (size_t)bc * LL;
  float s = 0.f, ss = 0.f;
  for (int i = threadIdx.x * 4; i < LL; i += 256 * 4) {
    float4 v = *(const float4*)(p + i);
    s += v.x + v.y + v.z + v.w;
    ss += v.x * v.x + v.y * v.y + v.z * v.z + v.w * v.w;
  }
  for (int o = 32; o > 0; o >>= 1) {
    s += __shfl_down(s, o, 64);
    ss += __shfl_down(ss, o, 64);
  }
  __shared__ float sb[4], ssb[4];
  int wid = threadIdx.x >> 6;
  if ((threadIdx.x & 63) == 0) { sb[wid] = s; ssb[wid] = ss; }
  __syncthreads();
  if (threadIdx.x == 0) {
    s = sb[0] + sb[1] + sb[2] + sb[3];
    ss = ssb[0] + ssb[1] + ssb[2] + ssb[3];
    float m = s * (1.f / LL);
    float var = ss * (1.f / LL) - m * m;
    mu[bc] = m;
    rstd[bc] = 1.f / sqrtf(var + 1e-5f);
  }
}

// ---------------------------------------------------------------------------
// xT[b][t][c] bf16 = normalized x (LDS 64x64 transpose tile)
__global__ __launch_bounds__(256) void xt_norm_kernel(
    const float* __restrict__ x, const float* __restrict__ mu,
    const float* __restrict__ rstd, ushort_t* __restrict__ xT) {
  __shared__ ushort_t T[64][72];
  int t0 = blockIdx.x * 64, c0 = blockIdx.y * 64, b = blockIdx.z;
  int tid = threadIdx.x;
  int c = tid >> 2, tq = (tid & 3) * 16;
  int bc = b * CM + c0 + c;
  const float* xp = x + (size_t)bc * LL + t0 + tq;
  float m = mu[bc], rs = rstd[bc];
  #pragma unroll
  for (int j = 0; j < 16; j += 4) {
    float4 v = *(const float4*)(xp + j);
    T[c][tq + j + 0] = f2bf((v.x - m) * rs);
    T[c][tq + j + 1] = f2bf((v.y - m) * rs);
    T[c][tq + j + 2] = f2bf((v.z - m) * rs);
    T[c][tq + j + 3] = f2bf((v.w - m) * rs);
  }
  __syncthreads();
  int t = tid >> 2, cq = (tid & 3) * 16;
  unsigned int ob[8];
  #pragma unroll
  for (int j = 0; j < 8; j++)
    ob[j] = (unsigned int)T[cq + 2 * j][t] | ((unsigned int)T[cq + 2 * j + 1][t] << 16);
  ushort_t* op = xT + ((size_t)b * LL + t0 + t) * CM + c0 + cq;
  *(uint4*)(op)     = make_uint4(ob[0], ob[1], ob[2], ob[3]);
  *(uint4*)(op + 8) = make_uint4(ob[4], ob[5], ob[6], ob[7]);
}

// ---------------------------------------------------------------------------
// MFMA bf16 GEMM.  A[Mp][K] bf16 row-major (weights, Mp mult of 64).
// BT[b][N][K] bf16 row-major (activations, time-major).
// TOUT=true : C[b][n][m] (time-major out, ldc = m-stride of a t-row)
// TOUT=false: C[b][m][n] (+bias[m])
// Block: 256 thr = 4 waves; tile M=64 x N=128 (wave: 64x32). No LDS.
template <bool TOUT, typename OutT>
__global__ __launch_bounds__(256) void gemm_mfma(
    const ushort_t* __restrict__ A, const ushort_t* __restrict__ BT,
    OutT* __restrict__ C, int K, long strideBT, long strideC, int ldc,
    const float* __restrict__ bias) {
  int lane = threadIdx.x & 63;
  int wave = threadIdx.x >> 6;
  int m0 = blockIdx.x * 64;
  long n0 = (long)blockIdx.y * 128 + wave * 32;
  int b = blockIdx.z;
  int r = lane & 15;
  int ko = (lane >> 4) * 8;
  const ushort_t* Ap = A + (size_t)(m0 + r) * K + ko;
  const ushort_t* Bp = BT + (size_t)b * strideBT + (size_t)(n0 + r) * K + ko;

  f32x4 acc[4][2];
  #pragma unroll
  for (int mi = 0; mi < 4; mi++)
    #pragma unroll
    for (int ni = 0; ni < 2; ni++) acc[mi][ni] = (f32x4){0.f, 0.f, 0.f, 0.f};

  for (int k0 = 0; k0 < K; k0 += 32) {
    bf16x8 fa[4], fb[2];
    #pragma unroll
    for (int mi = 0; mi < 4; mi++)
      fa[mi] = *(const bf16x8*)(Ap + (size_t)mi * 16 * K + k0);
    #pragma unroll
    for (int ni = 0; ni < 2; ni++)
      fb[ni] = *(const bf16x8*)(Bp + (size_t)ni * 16 * K + k0);
    #pragma unroll
    for (int mi = 0; mi < 4; mi++)
      #pragma unroll
      for (int ni = 0; ni < 2; ni++) {
        if constexpr (TOUT)
          acc[mi][ni] = __builtin_amdgcn_mfma_f32_16x16x32_bf16(fb[ni], fa[mi], acc[mi][ni], 0, 0, 0);
        else
          acc[mi][ni] = __builtin_amdgcn_mfma_f32_16x16x32_bf16(fa[mi], fb[ni], acc[mi][ni], 0, 0, 0);
      }
  }
  int cq = (lane >> 4) * 4;
  if constexpr (TOUT) {
    #pragma unroll
    for (int ni = 0; ni < 2; ni++)
      #pragma unroll
      for (int rg = 0; rg < 4; rg++) {
        long n = n0 + ni * 16 + cq + rg;
        OutT* cp = C + (size_t)b * strideC + n * ldc + m0 + (lane & 15);
        #pragma unroll
        for (int mi = 0; mi < 4; mi++) {
          float v = acc[mi][ni][rg];
          if constexpr (sizeof(OutT) == 2) cp[mi * 16] = f2bf(v);
          else                             cp[mi * 16] = v;
        }
      }
  } else {
    #pragma unroll
    for (int mi = 0; mi < 4; mi++)
      #pragma unroll
      for (int rg = 0; rg < 4; rg++) {
        int m = m0 + mi * 16 + cq + rg;
        float bv = bias ? bias[m] : 0.f;
        OutT* cp = C + (size_t)b * strideC + (size_t)m * ldc + n0 + (lane & 15);
        #pragma unroll
        for (int ni = 0; ni < 2; ni++)
          cp[ni * 16] = acc[mi][ni][rg] + bv;
      }
  }
}

// ---------------------------------------------------------------------------
// Conv: causal depthwise k=4 + bias + SiLU.  LDS-staged xzT u-half rows
// (coalesced), 32 t per block, all 384 d. Writes u_t[b][t][d] bf16.
__global__ __launch_bounds__(384) void conv_silu_kernel(
    const ushort_t* __restrict__ xzT, const float* __restrict__ conv_w,
    const float* __restrict__ conv_b, ushort_t* __restrict__ u_t) {
  __shared__ ushort_t Us[CVT + 3][DI];
  int t0 = blockIdx.x * CVT;
  int b = blockIdx.y;
  int tid = threadIdx.x;          // d
  #pragma unroll
  for (int r = 0; r < CVT + 3; r++) {
    int t = t0 - 3 + r;
    Us[r][tid] = (t >= 0) ? xzT[((size_t)b * LL + t) * XZS + tid] : (ushort_t)0;
  }
  float w0 = conv_w[tid * 4 + 0], w1 = conv_w[tid * 4 + 1];
  float w2 = conv_w[tid * 4 + 2], w3 = conv_w[tid * 4 + 3];
  float cb = conv_b[tid];
  __syncthreads();
  ushort_t* up = u_t + ((size_t)b * LL + t0) * DI + tid;
  float xm3 = bf2f(Us[0][tid]);
  float xm2 = bf2f(Us[1][tid]);
  float xm1 = bf2f(Us[2][tid]);
  #pragma unroll
  for (int t = 0; t < CVT; t++) {
    float xc = bf2f(Us[t + 3][tid]);
    float a = cb + w3 * xc + w2 * xm1 + w1 * xm2 + w0 * xm3;
    float sv = a / (1.f + __expf(-a));
    up[(size_t)t * DI] = f2bf(sv);
    xm3 = xm2; xm2 = xm1; xm1 = xc;
  }
}

// ---------------------------------------------------------------------------
// dt_t[b][t][d] fp32 = softplus(dt_proj_w @ dblT[t][0..11] + dt_proj_b)
// 32 t per block, LDS-staged dt_low, fast softplus.
__global__ __launch_bounds__(384) void dt_kernel(
    const float* __restrict__ dblT, const float* __restrict__ dtw,
    const float* __restrict__ dtb, float* __restrict__ dt_t) {
  __shared__ float Ls[DTT * 12];
  int t0 = blockIdx.x * DTT;
  int b = blockIdx.y;
  int tid = threadIdx.x;          // d
  if (tid < DTT * 12) {
    int t = tid / 12, rr = tid - t * 12;
    Ls[tid] = dblT[((size_t)b * LL + t0 + t) * DBS + rr];
  }
  float dw[12];
  #pragma unroll
  for (int rr = 0; rr < 12; rr += 4)
    *(float4*)(dw + rr) = *(const float4*)(dtw + tid * 12 + rr);
  float db = dtb[tid];
  __syncthreads();
  float* op = dt_t + ((size_t)b * LL + t0) * DI + tid;
  #pragma unroll
  for (int t = 0; t < DTT; t++) {
    float acc = db;
    #pragma unroll
    for (int rr = 0; rr < 12; rr++) acc = fmaf(Ls[t * 12 + rr], dw[rr], acc);
    float v = (acc > 15.f) ? acc : __logf(1.f + __expf(acc));
    op[(size_t)t * DI] = v;
  }
}

// ---------------------------------------------------------------------------
// Scan phase 1: block=(chunk,b), 384 thr = 1 per channel d, 16 states/thread.
// B read via uniform-address loads (scalar-cache broadcast; no threadIdx in
// the address). Decay powers via mul-tree (depth<=3). W = running product.
__global__ __launch_bounds__(384) void scan_phase1(
    const float* __restrict__ dt_t, const ushort_t* __restrict__ u_t,
    const float* __restrict__ dblT, const float* __restrict__ A_log,
    float* __restrict__ hend, float* __restrict__ Pbuf) {
  int tid = threadIdx.x;
  int chunk = blockIdx.x, b = blockIdx.y;
  int t0 = chunk * CLEN;
  const float* dblB = dblT + ((size_t)b * LL + t0) * DBS + RDT;  // uniform base
  int d = tid;
  int bd = b * DI + d;
  float av0 = -expf(A_log[d * NST]);
  float av_[NST];
  bool ok = true;
  #pragma unroll
  for (int j = 0; j < NST; j++) {
    av_[j] = -expf(A_log[d * NST + j]);
    ok = ok && (fabsf(av_[j] - av0 * (float)(j + 1)) <= 1e-4f * fabsf(av_[j]));
  }
  const float* dtp = dt_t + ((size_t)b * LL + t0) * DI + d;
  const ushort_t* up = u_t + ((size_t)b * LL + t0) * DI + d;
  float h[NST];
  #pragma unroll
  for (int j = 0; j < NST; j++) h[j] = 0.f;

  size_t o = ((size_t)bd * NC + chunk) * NST;
  if (__all(ok)) {
    float W = 1.f;
    #pragma unroll 2
    for (int t = 0; t < CLEN; t++) {
      float dtv = dtp[(size_t)t * DI];
      float uv  = bf2f(up[(size_t)t * DI]);
      float4 B0 = *(const float4*)(dblB + t * DBS + 0);
      float4 B1 = *(const float4*)(dblB + t * DBS + 4);
      float4 B2 = *(const float4*)(dblB + t * DBS + 8);
      float4 B3 = *(const float4*)(dblB + t * DBS + 12);
      float q = dtv * uv;
      float p1 = __expf(dtv * av0);
      W *= p1;
      float p2 = p1 * p1, p4 = p2 * p2, p8 = p4 * p4;
      float p3 = p2 * p1, p5 = p4 * p1, p6 = p4 * p2, p7 = p4 * p3;
      h[0]  = fmaf(p1, h[0],  q * B0.x);
      h[1]  = fmaf(p2, h[1],  q * B0.y);
      h[2]  = fmaf(p3, h[2],  q * B0.z);
      h[3]  = fmaf(p4, h[3],  q * B0.w);
      h[4]  = fmaf(p5, h[4],  q * B1.x);
      h[5]  = fmaf(p6, h[5],  q * B1.y);
      h[6]  = fmaf(p7, h[6],  q * B1.z);
      h[7]  = fmaf(p8, h[7],  q * B1.w);
      h[8]  = fmaf(p8 * p1, h[8],  q * B2.x);
      h[9]  = fmaf(p8 * p2, h[9],  q * B2.y);
      h[10] = fmaf(p8 * p3, h[10], q * B2.z);
      h[11] = fmaf(p8 * p4, h[11], q * B2.w);
      h[12] = fmaf(p8 * p5, h[12], q * B3.x);
      h[13] = fmaf(p8 * p6, h[13], q * B3.y);
      h[14] = fmaf(p8 * p7, h[14], q * B3.z);
      h[15] = fmaf(p8 * p8, h[15], q * B3.w);
    }
    #pragma unroll
    for (int j = 0; j < NST; j += 4)
      *(float4*)(hend + o + j) = make_float4(h[j], h[j+1], h[j+2], h[j+3]);
    float P[NST];
    float pj = W;
    #pragma unroll
    for (int j = 0; j < NST; j++) { P[j] = pj; pj *= W; }
    #pragma unroll
    for (int j = 0; j < NST; j += 4)
      *(float4*)(Pbuf + o + j) = make_float4(P[j], P[j+1], P[j+2], P[j+3]);
  } else {
    float S = 0.f;
    for (int t = 0; t < CLEN; t++) {
      float dtv = dtp[(size_t)t * DI];
      float uv  = bf2f(up[(size_t)t * DI]);
      float q = dtv * uv;
      S += dtv;
      #pragma unroll
      for (int j = 0; j < NST; j++)
        h[j] = __expf(dtv * av_[j]) * h[j] + q * dblB[t * DBS + j];
    }
    #pragma unroll
    for (int j = 0; j < NST; j++) {
      hend[o + j] = h[j];
      Pbuf[o + j] = __expf(S * av_[j]);
    }
  }
}

// ---------------------------------------------------------------------------
// Scan combine: block per bd (768 blocks), 256 thr = (g=tid>>4 chunk-group,
// s=tid&15 state). Serial compose NCH chunks/thread, LDS exclusive scan over
// groups, replay writing carry-in into hend.
__global__ __launch_bounds__(256) void scan_combine(
    float* __restrict__ hend, const float* __restrict__ Pbuf) {
  __shared__ float sP[16][16], sH[16][16];
  int bd = blockIdx.x;
  int s = threadIdx.x & 15, g = threadIdx.x >> 4;
  size_t base = ((size_t)bd * NC + g * NCH) * NST + s;
  // pass 1: local compose
  float Pl = 1.f, Hl = 0.f;
  #pragma unroll
  for (int k = 0; k < NCH; k++) {
    size_t o = base + (size_t)k * NST;
    float p = Pbuf[o], he = hend[o];
    Hl = fmaf(p, Hl, he);
    Pl *= p;
  }
  sP[g][s] = Pl; sH[g][s] = Hl;
  __syncthreads();
  // exclusive scan over g (16 threads serial, one per s)
  if (threadIdx.x < 16) {
    int ss = threadIdx.x;
    float c = 0.f;
    #pragma unroll
    for (int gg = 0; gg < 16; gg++) {
      float tmp = sH[gg][ss];
      float pp  = sP[gg][ss];
      sH[gg][ss] = c;
      c = fmaf(pp, c, tmp);
    }
  }
  __syncthreads();
  // pass 2: replay with carry, store exclusive prefix into hend
  float c = sH[g][s];
  #pragma unroll
  for (int k = 0; k < NCH; k++) {
    size_t o = base + (size_t)k * NST;
    float p = Pbuf[o], he = hend[o];
    hend[o] = c;
    c = fmaf(p, c, he);
  }
}

// ---------------------------------------------------------------------------
// Scan phase 3: 1 thread per channel, 16 states; uniform-address B/C loads;
// power-tree decay; ym_t[b][t][d] bf16 = (y + u*D) * silu(z).
__global__ __launch_bounds__(384) void scan_phase3(
    const float* __restrict__ dt_t, const ushort_t* __restrict__ u_t,
    const float* __restrict__ dblT, const float* __restrict__ A_log,
    const float* __restrict__ hin, const float* __restrict__ Dp,
    const ushort_t* __restrict__ xzT, ushort_t* __restrict__ ym_t) {
  int tid = threadIdx.x;
  int chunk = blockIdx.x, b = blockIdx.y;
  int t0 = chunk * CLEN;
  const float* dblB = dblT + ((size_t)b * LL + t0) * DBS + RDT;  // uniform base
  int d = tid;
  int bd = b * DI + d;
  float av0 = -expf(A_log[d * NST]);
  float av_[NST];
  bool ok = true;
  #pragma unroll
  for (int j = 0; j < NST; j++) {
    av_[j] = -expf(A_log[d * NST + j]);
    ok = ok && (fabsf(av_[j] - av0 * (float)(j + 1)) <= 1e-4f * fabsf(av_[j]));
  }
  const float* dtp = dt_t + ((size_t)b * LL + t0) * DI + d;
  const ushort_t* up = u_t + ((size_t)b * LL + t0) * DI + d;
  const ushort_t* zp = xzT + ((size_t)b * LL + t0) * XZS + DI + d;
  ushort_t* ymp = ym_t + ((size_t)b * LL + t0) * DI + d;

  float h[NST];
  const float* hi = hin + ((size_t)bd * NC + chunk) * NST;
  #pragma unroll
  for (int j = 0; j < NST; j += 4) {
    float4 v = *(const float4*)(hi + j);
    h[j] = v.x; h[j+1] = v.y; h[j+2] = v.z; h[j+3] = v.w;
  }
  float Dv = Dp[d];

  if (__all(ok)) {
    #pragma unroll 2
    for (int t = 0; t < CLEN; t++) {
      float dtv = dtp[(size_t)t * DI];
      float uv  = bf2f(up[(size_t)t * DI]);
      float zv  = bf2f(zp[(size_t)t * XZS]);
      float4 B0 = *(const float4*)(dblB + t * DBS + 0);
      float4 B1 = *(const float4*)(dblB + t * DBS + 4);
      float4 B2 = *(const float4*)(dblB + t * DBS + 8);
      float4 B3 = *(const float4*)(dblB + t * DBS + 12);
      float4 C0 = *(const float4*)(dblB + t * DBS + 16);
      float4 C1 = *(const float4*)(dblB + t * DBS + 20);
      float4 C2 = *(const float4*)(dblB + t * DBS + 24);
      float4 C3 = *(const float4*)(dblB + t * DBS + 28);
      float q = dtv * uv;
      float p1 = __expf(dtv * av0);
      float p2 = p1 * p1, p4 = p2 * p2, p8 = p4 * p4;
      float p3 = p2 * p1, p5 = p4 * p1, p6 = p4 * p2, p7 = p4 * p3;
      float y0, y1, y2, y3;
      h[0]  = fmaf(p1, h[0],  q * B0.x); y0 = h[0] * C0.x;
      h[1]  = fmaf(p2, h[1],  q * B0.y); y1 = h[1] * C0.y;
      h[2]  = fmaf(p3, h[2],  q * B0.z); y2 = h[2] * C0.z;
      h[3]  = fmaf(p4, h[3],  q * B0.w); y3 = h[3] * C0.w;
      h[4]  = fmaf(p5, h[4],  q * B1.x); y0 = fmaf(h[4],  C1.x, y0);
      h[5]  = fmaf(p6, h[5],  q * B1.y); y1 = fmaf(h[5],  C1.y, y1);
      h[6]  = fmaf(p7, h[6],  q * B1.z); y2 = fmaf(h[6],  C1.z, y2);
      h[7]  = fmaf(p8, h[7],  q * B1.w); y3 = fmaf(h[7],  C1.w, y3);
      h[8]  = fmaf(p8 * p1, h[8],  q * B2.x); y0 = fmaf(h[8],  C2.x, y0);
      h[9]  = fmaf(p8 * p2, h[9],  q * B2.y); y1 = fmaf(h[9],  C2.y, y1);
      h[10] = fmaf(p8 * p3, h[10], q * B2.z); y2 = fmaf(h[10], C2.z, y2);
      h[11] = fmaf(p8 * p4, h[11], q * B2.w); y3 = fmaf(h[11], C2.w, y3);
      h[12] = fmaf(p8 * p5, h[12], q * B3.x); y0 = fmaf(h[12], C3.x, y0);
      h[13] = fmaf(p8 * p6, h[13], q * B3.y); y1 = fmaf(h[13], C3.y, y1);
      h[14] = fmaf(p8 * p7, h[14], q * B3.z); y2 = fmaf(h[14], C3.z, y2);
      h[15] = fmaf(p8 * p8, h[15], q * B3.w); y3 = fmaf(h[15], C3.w, y3);
      float y = (y0 + y1) + (y2 + y3);
      float yv = (y + uv * Dv) * (zv / (1.f + __expf(-zv)));
      ymp[(size_t)t * DI] = f2bf(yv);
    }
  } else {
    for (int t = 0; t < CLEN; t++) {
      float dtv = dtp[(size_t)t * DI];
      float uv  = bf2f(up[(size_t)t * DI]);
      float zv  = bf2f(zp[(size_t)t * XZS]);
      float q = dtv * uv;
      float y = 0.f;
      #pragma unroll
      for (int j = 0; j < NST; j++) {
        h[j] = __expf(dtv * av_[j]) * h[j] + q * dblB[t * DBS + j];
        y = fmaf(h[j], dblB[t * DBS + NST + j], y);
      }
      float yv = (y + uv * Dv) * (zv / (1.f + __expf(-zv)));
      ymp[(size_t)t * DI] = f2bf(yv);
    }
  }
}

// ---------------------------------------------------------------------------
extern "C" void kernel_launch(void* const* d_in, const int* in_sizes, int n_in,
                              void* d_out, int out_size, void* d_ws, size_t ws_size,
                              hipStream_t stream) {
  const float* x         = (const float*)d_in[0];
  const float* in_proj_w = (const float*)d_in[1];
  const float* conv_w    = (const float*)d_in[2];
  const float* conv_b    = (const float*)d_in[3];
  const float* x_proj_w  = (const float*)d_in[4];
  const float* dt_proj_w = (const float*)d_in[5];
  const float* dt_proj_b = (const float*)d_in[6];
  const float* A_log     = (const float*)d_in[7];
  const float* D_param   = (const float*)d_in[8];
  const float* out_proj_w= (const float*)d_in[9];
  const float* proj_w    = (const float*)d_in[10];
  const float* proj_b    = (const float*)d_in[11];
  float* out = (float*)d_out;

  // workspace layout (float units)
  float* w = (float*)d_ws;
  float*    mu     = w;                                   // 512
  float*    rstd   = w + 512;                             // 512
  float*    PW     = w + 1024;                            // 73,728
  ushort_t* PW_bf  = (ushort_t*)(w + 74752);              // 73,728 bf16 (36,864 f)
  ushort_t* ipw_bf = (ushort_t*)(w + 111616);             // 147,456 bf16 (73,728 f)
  ushort_t* xpw_bf = (ushort_t*)(w + 185344);             // 24,576 bf16 (12,288 f)
  ushort_t* xT     = (ushort_t*)(w + 197632);             // 6.29M bf16 (3,145,728 f)
  ushort_t* xzT    = (ushort_t*)(w + 3343360);            // 25.2M bf16 (12,582,912 f)
  ushort_t* u_t    = (ushort_t*)(w + 15926272);           // 12.6M bf16 (6,291,456 f)
  float*    dblT   = w + 22217728;                        // 2,097,152 f
  float*    dt_t   = w + 24314880;                        // 12,582,912 f
  ushort_t* ym_t   = (ushort_t*)(w + 36897792);           // 12.6M bf16 (6,291,456 f)
  float*    hend   = w + 43189248;                        // 6,291,456 f (NC=512)
  float*    Pbuf   = w + 49480704;                        // 6,291,456 f
  size_t need = 55772160;
  if (ws_size < need * sizeof(float)) return;

  norm_stats_kernel<<<dim3(BB * CM), dim3(256), 0, stream>>>(x, mu, rstd);
  fuse_proj_kernel<<<dim3((CM * DI + 255) / 256), dim3(256), 0, stream>>>(proj_w, out_proj_w, PW);
  cvt_weights_kernel<<<dim3((2 * DI * CM + 255) / 256), dim3(256), 0, stream>>>(
      in_proj_w, x_proj_w, PW, ipw_bf, xpw_bf, PW_bf);
  xt_norm_kernel<<<dim3(LL / 64, CM / 64, BB), dim3(256), 0, stream>>>(x, mu, rstd, xT);

  // GEMM1: xzT[b][t][768] = xT(BT) x in_proj_w   (M=768, K=192)
  gemm_mfma<true, ushort_t><<<dim3(12, 128, BB), dim3(256), 0, stream>>>(
      ipw_bf, xT, xzT, CM, (long)LL * CM, (long)LL * XZS, XZS, nullptr);

  conv_silu_kernel<<<dim3(LL / CVT, BB), dim3(384), 0, stream>>>(xzT, conv_w, conv_b, u_t);

  // GEMM2: dblT[b][t][64] = u_t(BT) x x_proj_w(padded)  (M=64, K=384)
  gemm_mfma<true, float><<<dim3(1, 128, BB), dim3(256), 0, stream>>>(
      xpw_bf, u_t, dblT, DI, (long)LL * DI, (long)LL * DBS, DBS, nullptr);

  dt_kernel<<<dim3(LL / DTT, BB), dim3(384), 0, stream>>>(dblT, dt_proj_w, dt_proj_b, dt_t);

  scan_phase1<<<dim3(NC, BB), dim3(384), 0, stream>>>(dt_t, u_t, dblT, A_log, hend, Pbuf);
  scan_combine<<<dim3(BB * DI), dim3(256), 0, stream>>>(hend, Pbuf);
  scan_phase3<<<dim3(NC, BB), dim3(384), 0, stream>>>(dt_t, u_t, dblT, A_log, hend, D_param, xzT, ym_t);

  // GEMM3: out[b][192][L] = PW x ym_t(BT) + proj_b  (M=192, K=384)
  gemm_mfma<false, float><<<dim3(3, 128, BB), dim3(256), 0, stream>>>(
      PW_bf, ym_t, out, DI, (long)LL * DI, (long)CM * LL, LL, proj_b);
}

// Round 8
// 226.809 us; speedup vs baseline: 1.1963x; 1.1963x over previous
//
#include <hip/hip_runtime.h>
#include <hip/hip_bf16.h>
#include <math.h>

// Problem constants
#define BB   2
#define CM   192        // D_MODEL
#define DI   384        // D_INNER
#define LL   16384      // D*H*W
#define NST  16         // D_STATE
#define RDT  12         // DT_RANK
#define XJ   44         // DT_RANK + 2*D_STATE
#define NC   512        // scan chunks
#define CLEN 32         // chunk length (NC*CLEN == LL)
#define NCH  (NC / 16)  // chunks per combine-thread
#define DBS  64         // dblT row stride (GEMM2 padded M)
#define XZS  768        // xzT row stride
#define CVT  32         // conv t-tile
#define DTT  32         // dt t-tile
#define BK   32         // GEMM k-tile

typedef __attribute__((ext_vector_type(8))) short bf16x8;
typedef __attribute__((ext_vector_type(4))) float f32x4;
typedef unsigned short ushort_t;

static __device__ __forceinline__ ushort_t f2bf(float f) {
  __hip_bfloat16 h = __float2bfloat16(f);
  return *reinterpret_cast<ushort_t*>(&h);
}
static __device__ __forceinline__ float bf2f(ushort_t u) {
  __hip_bfloat16 h;
  *reinterpret_cast<ushort_t*>(&h) = u;
  return __bfloat162float(h);
}

// ---------------------------------------------------------------------------
// PW = proj_w(192x192) @ out_proj_w(192x384)   (fp32, tiny)
__global__ __launch_bounds__(256) void fuse_proj_kernel(
    const float* __restrict__ pw, const float* __restrict__ ow, float* __restrict__ PW) {
  int idx = blockIdx.x * 256 + threadIdx.x;
  if (idx >= CM * DI) return;
  int o = idx / DI, d = idx % DI;
  float s = 0.f;
  #pragma unroll 4
  for (int c = 0; c < CM; c++) s += pw[o * CM + c] * ow[c * DI + d];
  PW[idx] = s;
}

// ---------------------------------------------------------------------------
// Weight conversions to bf16. Row-padding with zeros:
// ipw_bf 768x192 (exact), xpw_bf 128x384 (rows>=44 zero), PW_bf 256x384 (rows>=192 zero)
__global__ __launch_bounds__(256) void cvt_weights_kernel(
    const float* __restrict__ ipw, const float* __restrict__ xpw,
    const float* __restrict__ PW,
    ushort_t* __restrict__ ipw_bf, ushort_t* __restrict__ xpw_bf,
    ushort_t* __restrict__ PW_bf) {
  int i = blockIdx.x * 256 + threadIdx.x;
  if (i < 2 * DI * CM) ipw_bf[i] = f2bf(ipw[i]);
  if (i < 128 * DI) {
    int r = i / DI;
    xpw_bf[i] = (r < XJ) ? f2bf(xpw[i]) : (ushort_t)0;
  }
  if (i < 256 * DI) {
    int r = i / DI;
    PW_bf[i] = (r < CM) ? f2bf(PW[i]) : (ushort_t)0;
  }
}

// ---------------------------------------------------------------------------
// per-(b,c) mean / rstd over L
__global__ __launch_bounds__(256) void norm_stats_kernel(
    const float* __restrict__ x, float* __restrict__ mu, float* __restrict__ rstd) {
  int bc = blockIdx.x;
  const float* p = x + (size_t)bc * LL;
  float s = 0.f, ss = 0.f;
  for (int i = threadIdx.x * 4; i < LL; i += 256 * 4) {
    float4 v = *(const float4*)(p + i);
    s += v.x + v.y + v.z + v.w;
    ss += v.x * v.x + v.y * v.y + v.z * v.z + v.w * v.w;
  }
  for (int o = 32; o > 0; o >>= 1) {
    s += __shfl_down(s, o, 64);
    ss += __shfl_down(ss, o, 64);
  }
  __shared__ float sb[4], ssb[4];
  int wid = threadIdx.x >> 6;
  if ((threadIdx.x & 63) == 0) { sb[wid] = s; ssb[wid] = ss; }
  __syncthreads();
  if (threadIdx.x == 0) {
    s = sb[0] + sb[1] + sb[2] + sb[3];
    ss = ssb[0] + ssb[1] + ssb[2] + ssb[3];
    float m = s * (1.f / LL);
    float var = ss * (1.f / LL) - m * m;
    mu[bc] = m;
    rstd[bc] = 1.f / sqrtf(var + 1e-5f);
  }
}

// ---------------------------------------------------------------------------
// xT[b][t][c] bf16 = normalized x (LDS 64x64 transpose tile)
__global__ __launch_bounds__(256) void xt_norm_kernel(
    const float* __restrict__ x, const float* __restrict__ mu,
    const float* __restrict__ rstd, ushort_t* __restrict__ xT) {
  __shared__ ushort_t T[64][72];
  int t0 = blockIdx.x * 64, c0 = blockIdx.y * 64, b = blockIdx.z;
  int tid = threadIdx.x;
  int c = tid >> 2, tq = (tid & 3) * 16;
  int bc = b * CM + c0 + c;
  const float* xp = x + (size_t)bc * LL + t0 + tq;
  float m = mu[bc], rs = rstd[bc];
  #pragma unroll
  for (int j = 0; j < 16; j += 4) {
    float4 v = *(const float4*)(xp + j);
    T[c][tq + j + 0] = f2bf((v.x - m) * rs);
    T[c][tq + j + 1] = f2bf((v.y - m) * rs);
    T[c][tq + j + 2] = f2bf((v.z - m) * rs);
    T[c][tq + j + 3] = f2bf((v.w - m) * rs);
  }
  __syncthreads();
  int t = tid >> 2, cq = (tid & 3) * 16;
  unsigned int ob[8];
  #pragma unroll
  for (int j = 0; j < 8; j++)
    ob[j] = (unsigned int)T[cq + 2 * j][t] | ((unsigned int)T[cq + 2 * j + 1][t] << 16);
  ushort_t* op = xT + ((size_t)b * LL + t0 + t) * CM + c0 + cq;
  *(uint4*)(op)     = make_uint4(ob[0], ob[1], ob[2], ob[3]);
  *(uint4*)(op + 8) = make_uint4(ob[4], ob[5], ob[6], ob[7]);
}

// ---------------------------------------------------------------------------
// LDS-pipelined MFMA bf16 GEMM (m97-style, BK=32 double-buffer, global_load_lds).
// A[Mp][K] bf16 row-major, Mp = MT*128 (zero-padded). BT[b][N][K] bf16.
// 1D grid = 256*MT blocks; MT m-tiles of one n-tile co-located on one XCD.
// TOUT=true : C[b][n][m] (ldc = row stride); TOUT=false: C[b][m][n] (+bias[m]).
template <bool TOUT, typename OutT>
__global__ __launch_bounds__(256) void gemm_lds(
    const ushort_t* __restrict__ A, const ushort_t* __restrict__ BT,
    OutT* __restrict__ C, int K, int Mreal, int MT,
    long strideBT, long strideC, int ldc,
    const float* __restrict__ bias) {
  __shared__ ushort_t Asm[2][128 * BK];
  __shared__ ushort_t Bsm[2][128 * BK];

  // block decode with XCD co-location (ids equal mod 8 share an XCD)
  int id = blockIdx.x;
  int per = MT * 8;
  int g = id / per, r = id % per;
  int nt = g * 8 + (r & 7);       // global n-tile in [0, 256)
  int mt = r >> 3;                // m-tile in [0, MT)
  int b  = nt >> 7;
  long n0 = (long)(nt & 127) * 128;
  int m0 = mt * 128;

  int tid = threadIdx.x;
  int lane = tid & 63, wave = tid >> 6;
  const ushort_t* Bbase = BT + (size_t)b * strideBT;

  // staging geometry: wave w issues 2 chunks; chunk c covers LDS rows
  // w*32 + c*16 + (lane>>2), 16B slot (lane&3)
  int srow0 = wave * 32 + (lane >> 2);
  int sk = (lane & 3) * 8;

  f32x4 acc[4][4];
  #pragma unroll
  for (int mi = 0; mi < 4; mi++)
    #pragma unroll
    for (int ni = 0; ni < 4; ni++) acc[mi][ni] = (f32x4){0.f, 0.f, 0.f, 0.f};

  int mh = wave & 1, nh = wave >> 1;   // wave's 64x64 quadrant
  int fr = lane & 15, fk = (lane >> 4) * 8;

  int nsteps = K / BK;
  // prologue
  {
    const ushort_t* As0 = A + (size_t)(m0 + srow0) * K + sk;
    const ushort_t* Bs0 = Bbase + (size_t)(n0 + srow0) * K + sk;
    __builtin_amdgcn_global_load_lds(As0, &Asm[0][wave * 1024], 16, 0, 0);
    __builtin_amdgcn_global_load_lds(As0 + (size_t)16 * K, &Asm[0][wave * 1024 + 512], 16, 0, 0);
    __builtin_amdgcn_global_load_lds(Bs0, &Bsm[0][wave * 1024], 16, 0, 0);
    __builtin_amdgcn_global_load_lds(Bs0 + (size_t)16 * K, &Bsm[0][wave * 1024 + 512], 16, 0, 0);
  }
  __syncthreads();
  int cur = 0;
  for (int s = 0; s < nsteps; s++) {
    if (s + 1 < nsteps) {
      int k0 = (s + 1) * BK;
      const ushort_t* As0 = A + (size_t)(m0 + srow0) * K + k0 + sk;
      const ushort_t* Bs0 = Bbase + (size_t)(n0 + srow0) * K + k0 + sk;
      __builtin_amdgcn_global_load_lds(As0, &Asm[cur ^ 1][wave * 1024], 16, 0, 0);
      __builtin_amdgcn_global_load_lds(As0 + (size_t)16 * K, &Asm[cur ^ 1][wave * 1024 + 512], 16, 0, 0);
      __builtin_amdgcn_global_load_lds(Bs0, &Bsm[cur ^ 1][wave * 1024], 16, 0, 0);
      __builtin_amdgcn_global_load_lds(Bs0 + (size_t)16 * K, &Bsm[cur ^ 1][wave * 1024 + 512], 16, 0, 0);
    }
    bf16x8 fa[4], fb[4];
    #pragma unroll
    for (int mi = 0; mi < 4; mi++)
      fa[mi] = *(const bf16x8*)&Asm[cur][(mh * 64 + mi * 16 + fr) * BK + fk];
    #pragma unroll
    for (int ni = 0; ni < 4; ni++)
      fb[ni] = *(const bf16x8*)&Bsm[cur][(nh * 64 + ni * 16 + fr) * BK + fk];
    #pragma unroll
    for (int mi = 0; mi < 4; mi++)
      #pragma unroll
      for (int ni = 0; ni < 4; ni++) {
        if constexpr (TOUT)
          acc[mi][ni] = __builtin_amdgcn_mfma_f32_16x16x32_bf16(fb[ni], fa[mi], acc[mi][ni], 0, 0, 0);
        else
          acc[mi][ni] = __builtin_amdgcn_mfma_f32_16x16x32_bf16(fa[mi], fb[ni], acc[mi][ni], 0, 0, 0);
      }
    __syncthreads();
    cur ^= 1;
  }

  int cq = (lane >> 4) * 4;
  if constexpr (TOUT) {
    #pragma unroll
    for (int ni = 0; ni < 4; ni++)
      #pragma unroll
      for (int rg = 0; rg < 4; rg++) {
        long n = n0 + nh * 64 + ni * 16 + cq + rg;
        OutT* cp = C + (size_t)b * strideC + n * ldc + m0 + mh * 64 + fr;
        #pragma unroll
        for (int mi = 0; mi < 4; mi++) {
          int mrow = m0 + mh * 64 + mi * 16 + fr;
          if (mrow < Mreal) {
            float v = acc[mi][ni][rg];
            if constexpr (sizeof(OutT) == 2) cp[mi * 16] = f2bf(v);
            else                             cp[mi * 16] = v;
          }
        }
      }
  } else {
    #pragma unroll
    for (int mi = 0; mi < 4; mi++)
      #pragma unroll
      for (int rg = 0; rg < 4; rg++) {
        int m = m0 + mh * 64 + mi * 16 + cq + rg;
        if (m < Mreal) {
          float bv = bias ? bias[m] : 0.f;
          OutT* cp = C + (size_t)b * strideC + (size_t)m * ldc + n0 + nh * 64 + fr;
          #pragma unroll
          for (int ni = 0; ni < 4; ni++)
            cp[ni * 16] = acc[mi][ni][rg] + bv;
        }
      }
  }
}

// ---------------------------------------------------------------------------
// Conv: causal depthwise k=4 + bias + SiLU.
__global__ __launch_bounds__(384) void conv_silu_kernel(
    const ushort_t* __restrict__ xzT, const float* __restrict__ conv_w,
    const float* __restrict__ conv_b, ushort_t* __restrict__ u_t) {
  __shared__ ushort_t Us[CVT + 3][DI];
  int t0 = blockIdx.x * CVT;
  int b = blockIdx.y;
  int tid = threadIdx.x;
  #pragma unroll
  for (int r = 0; r < CVT + 3; r++) {
    int t = t0 - 3 + r;
    Us[r][tid] = (t >= 0) ? xzT[((size_t)b * LL + t) * XZS + tid] : (ushort_t)0;
  }
  float w0 = conv_w[tid * 4 + 0], w1 = conv_w[tid * 4 + 1];
  float w2 = conv_w[tid * 4 + 2], w3 = conv_w[tid * 4 + 3];
  float cb = conv_b[tid];
  __syncthreads();
  ushort_t* up = u_t + ((size_t)b * LL + t0) * DI + tid;
  float xm3 = bf2f(Us[0][tid]);
  float xm2 = bf2f(Us[1][tid]);
  float xm1 = bf2f(Us[2][tid]);
  #pragma unroll
  for (int t = 0; t < CVT; t++) {
    float xc = bf2f(Us[t + 3][tid]);
    float a = cb + w3 * xc + w2 * xm1 + w1 * xm2 + w0 * xm3;
    float sv = a / (1.f + __expf(-a));
    up[(size_t)t * DI] = f2bf(sv);
    xm3 = xm2; xm2 = xm1; xm1 = xc;
  }
}

// ---------------------------------------------------------------------------
// dt_t[b][t][d] fp32 = softplus(dt_proj_w @ dblT[t][0..11] + dt_proj_b)
__global__ __launch_bounds__(384) void dt_kernel(
    const float* __restrict__ dblT, const float* __restrict__ dtw,
    const float* __restrict__ dtb, float* __restrict__ dt_t) {
  __shared__ float Ls[DTT * 12];
  int t0 = blockIdx.x * DTT;
  int b = blockIdx.y;
  int tid = threadIdx.x;
  if (tid < DTT * 12) {
    int t = tid / 12, rr = tid - t * 12;
    Ls[tid] = dblT[((size_t)b * LL + t0 + t) * DBS + rr];
  }
  float dw[12];
  #pragma unroll
  for (int rr = 0; rr < 12; rr += 4)
    *(float4*)(dw + rr) = *(const float4*)(dtw + tid * 12 + rr);
  float db = dtb[tid];
  __syncthreads();
  float* op = dt_t + ((size_t)b * LL + t0) * DI + tid;
  #pragma unroll
  for (int t = 0; t < DTT; t++) {
    float acc = db;
    #pragma unroll
    for (int rr = 0; rr < 12; rr++) acc = fmaf(Ls[t * 12 + rr], dw[rr], acc);
    float v = (acc > 15.f) ? acc : __logf(1.f + __expf(acc));
    op[(size_t)t * DI] = v;
  }
}

// ---------------------------------------------------------------------------
// Scan phase 1 (unchanged from R7)
__global__ __launch_bounds__(384) void scan_phase1(
    const float* __restrict__ dt_t, const ushort_t* __restrict__ u_t,
    const float* __restrict__ dblT, const float* __restrict__ A_log,
    float* __restrict__ hend, float* __restrict__ Pbuf) {
  int tid = threadIdx.x;
  int chunk = blockIdx.x, b = blockIdx.y;
  int t0 = chunk * CLEN;
  const float* dblB = dblT + ((size_t)b * LL + t0) * DBS + RDT;
  int d = tid;
  int bd = b * DI + d;
  float av0 = -expf(A_log[d * NST]);
  float av_[NST];
  bool ok = true;
  #pragma unroll
  for (int j = 0; j < NST; j++) {
    av_[j] = -expf(A_log[d * NST + j]);
    ok = ok && (fabsf(av_[j] - av0 * (float)(j + 1)) <= 1e-4f * fabsf(av_[j]));
  }
  const float* dtp = dt_t + ((size_t)b * LL + t0) * DI + d;
  const ushort_t* up = u_t + ((size_t)b * LL + t0) * DI + d;
  float h[NST];
  #pragma unroll
  for (int j = 0; j < NST; j++) h[j] = 0.f;

  size_t o = ((size_t)bd * NC + chunk) * NST;
  if (__all(ok)) {
    float W = 1.f;
    #pragma unroll 2
    for (int t = 0; t < CLEN; t++) {
      float dtv = dtp[(size_t)t * DI];
      float uv  = bf2f(up[(size_t)t * DI]);
      float4 B0 = *(const float4*)(dblB + t * DBS + 0);
      float4 B1 = *(const float4*)(dblB + t * DBS + 4);
      float4 B2 = *(const float4*)(dblB + t * DBS + 8);
      float4 B3 = *(const float4*)(dblB + t * DBS + 12);
      float q = dtv * uv;
      float p1 = __expf(dtv * av0);
      W *= p1;
      float p2 = p1 * p1, p4 = p2 * p2, p8 = p4 * p4;
      float p3 = p2 * p1, p5 = p4 * p1, p6 = p4 * p2, p7 = p4 * p3;
      h[0]  = fmaf(p1, h[0],  q * B0.x);
      h[1]  = fmaf(p2, h[1],  q * B0.y);
      h[2]  = fmaf(p3, h[2],  q * B0.z);
      h[3]  = fmaf(p4, h[3],  q * B0.w);
      h[4]  = fmaf(p5, h[4],  q * B1.x);
      h[5]  = fmaf(p6, h[5],  q * B1.y);
      h[6]  = fmaf(p7, h[6],  q * B1.z);
      h[7]  = fmaf(p8, h[7],  q * B1.w);
      h[8]  = fmaf(p8 * p1, h[8],  q * B2.x);
      h[9]  = fmaf(p8 * p2, h[9],  q * B2.y);
      h[10] = fmaf(p8 * p3, h[10], q * B2.z);
      h[11] = fmaf(p8 * p4, h[11], q * B2.w);
      h[12] = fmaf(p8 * p5, h[12], q * B3.x);
      h[13] = fmaf(p8 * p6, h[13], q * B3.y);
      h[14] = fmaf(p8 * p7, h[14], q * B3.z);
      h[15] = fmaf(p8 * p8, h[15], q * B3.w);
    }
    #pragma unroll
    for (int j = 0; j < NST; j += 4)
      *(float4*)(hend + o + j) = make_float4(h[j], h[j+1], h[j+2], h[j+3]);
    float P[NST];
    float pj = W;
    #pragma unroll
    for (int j = 0; j < NST; j++) { P[j] = pj; pj *= W; }
    #pragma unroll
    for (int j = 0; j < NST; j += 4)
      *(float4*)(Pbuf + o + j) = make_float4(P[j], P[j+1], P[j+2], P[j+3]);
  } else {
    float S = 0.f;
    for (int t = 0; t < CLEN; t++) {
      float dtv = dtp[(size_t)t * DI];
      float uv  = bf2f(up[(size_t)t * DI]);
      float q = dtv * uv;
      S += dtv;
      #pragma unroll
      for (int j = 0; j < NST; j++)
        h[j] = __expf(dtv * av_[j]) * h[j] + q * dblB[t * DBS + j];
    }
    #pragma unroll
    for (int j = 0; j < NST; j++) {
      hend[o + j] = h[j];
      Pbuf[o + j] = __expf(S * av_[j]);
    }
  }
}

// ---------------------------------------------------------------------------
// Scan combine (unchanged from R7)
__global__ __launch_bounds__(256) void scan_combine(
    float* __restrict__ hend, const float* __restrict__ Pbuf) {
  __shared__ float sP[16][16], sH[16][16];
  int bd = blockIdx.x;
  int s = threadIdx.x & 15, g = threadIdx.x >> 4;
  size_t base = ((size_t)bd * NC + g * NCH) * NST + s;
  float Pl = 1.f, Hl = 0.f;
  #pragma unroll
  for (int k = 0; k < NCH; k++) {
    size_t o = base + (size_t)k * NST;
    float p = Pbuf[o], he = hend[o];
    Hl = fmaf(p, Hl, he);
    Pl *= p;
  }
  sP[g][s] = Pl; sH[g][s] = Hl;
  __syncthreads();
  if (threadIdx.x < 16) {
    int ss = threadIdx.x;
    float c = 0.f;
    #pragma unroll
    for (int gg = 0; gg < 16; gg++) {
      float tmp = sH[gg][ss];
      float pp  = sP[gg][ss];
      sH[gg][ss] = c;
      c = fmaf(pp, c, tmp);
    }
  }
  __syncthreads();
  float c = sH[g][s];
  #pragma unroll
  for (int k = 0; k < NCH; k++) {
    size_t o = base + (size_t)k * NST;
    float p = Pbuf[o], he = hend[o];
    hend[o] = c;
    c = fmaf(p, c, he);
  }
}

// ---------------------------------------------------------------------------
// Scan phase 3 (unchanged from R7)
__global__ __launch_bounds__(384) void scan_phase3(
    const float* __restrict__ dt_t, const ushort_t* __restrict__ u_t,
    const float* __restrict__ dblT, const float* __restrict__ A_log,
    const float* __restrict__ hin, const float* __restrict__ Dp,
    const ushort_t* __restrict__ xzT, ushort_t* __restrict__ ym_t) {
  int tid = threadIdx.x;
  int chunk = blockIdx.x, b = blockIdx.y;
  int t0 = chunk * CLEN;
  const float* dblB = dblT + ((size_t)b * LL + t0) * DBS + RDT;
  int d = tid;
  int bd = b * DI + d;
  float av0 = -expf(A_log[d * NST]);
  float av_[NST];
  bool ok = true;
  #pragma unroll
  for (int j = 0; j < NST; j++) {
    av_[j] = -expf(A_log[d * NST + j]);
    ok = ok && (fabsf(av_[j] - av0 * (float)(j + 1)) <= 1e-4f * fabsf(av_[j]));
  }
  const float* dtp = dt_t + ((size_t)b * LL + t0) * DI + d;
  const ushort_t* up = u_t + ((size_t)b * LL + t0) * DI + d;
  const ushort_t* zp = xzT + ((size_t)b * LL + t0) * XZS + DI + d;
  ushort_t* ymp = ym_t + ((size_t)b * LL + t0) * DI + d;

  float h[NST];
  const float* hi = hin + ((size_t)bd * NC + chunk) * NST;
  #pragma unroll
  for (int j = 0; j < NST; j += 4) {
    float4 v = *(const float4*)(hi + j);
    h[j] = v.x; h[j+1] = v.y; h[j+2] = v.z; h[j+3] = v.w;
  }
  float Dv = Dp[d];

  if (__all(ok)) {
    #pragma unroll 2
    for (int t = 0; t < CLEN; t++) {
      float dtv = dtp[(size_t)t * DI];
      float uv  = bf2f(up[(size_t)t * DI]);
      float zv  = bf2f(zp[(size_t)t * XZS]);
      float4 B0 = *(const float4*)(dblB + t * DBS + 0);
      float4 B1 = *(const float4*)(dblB + t * DBS + 4);
      float4 B2 = *(const float4*)(dblB + t * DBS + 8);
      float4 B3 = *(const float4*)(dblB + t * DBS + 12);
      float4 C0 = *(const float4*)(dblB + t * DBS + 16);
      float4 C1 = *(const float4*)(dblB + t * DBS + 20);
      float4 C2 = *(const float4*)(dblB + t * DBS + 24);
      float4 C3 = *(const float4*)(dblB + t * DBS + 28);
      float q = dtv * uv;
      float p1 = __expf(dtv * av0);
      float p2 = p1 * p1, p4 = p2 * p2, p8 = p4 * p4;
      float p3 = p2 * p1, p5 = p4 * p1, p6 = p4 * p2, p7 = p4 * p3;
      float y0, y1, y2, y3;
      h[0]  = fmaf(p1, h[0],  q * B0.x); y0 = h[0] * C0.x;
      h[1]  = fmaf(p2, h[1],  q * B0.y); y1 = h[1] * C0.y;
      h[2]  = fmaf(p3, h[2],  q * B0.z); y2 = h[2] * C0.z;
      h[3]  = fmaf(p4, h[3],  q * B0.w); y3 = h[3] * C0.w;
      h[4]  = fmaf(p5, h[4],  q * B1.x); y0 = fmaf(h[4],  C1.x, y0);
      h[5]  = fmaf(p6, h[5],  q * B1.y); y1 = fmaf(h[5],  C1.y, y1);
      h[6]  = fmaf(p7, h[6],  q * B1.z); y2 = fmaf(h[6],  C1.z, y2);
      h[7]  = fmaf(p8, h[7],  q * B1.w); y3 = fmaf(h[7],  C1.w, y3);
      h[8]  = fmaf(p8 * p1, h[8],  q * B2.x); y0 = fmaf(h[8],  C2.x, y0);
      h[9]  = fmaf(p8 * p2, h[9],  q * B2.y); y1 = fmaf(h[9],  C2.y, y1);
      h[10] = fmaf(p8 * p3, h[10], q * B2.z); y2 = fmaf(h[10], C2.z, y2);
      h[11] = fmaf(p8 * p4, h[11], q * B2.w); y3 = fmaf(h[11], C2.w, y3);
      h[12] = fmaf(p8 * p5, h[12], q * B3.x); y0 = fmaf(h[12], C3.x, y0);
      h[13] = fmaf(p8 * p6, h[13], q * B3.y); y1 = fmaf(h[13], C3.y, y1);
      h[14] = fmaf(p8 * p7, h[14], q * B3.z); y2 = fmaf(h[14], C3.z, y2);
      h[15] = fmaf(p8 * p8, h[15], q * B3.w); y3 = fmaf(h[15], C3.w, y3);
      float y = (y0 + y1) + (y2 + y3);
      float yv = (y + uv * Dv) * (zv / (1.f + __expf(-zv)));
      ymp[(size_t)t * DI] = f2bf(yv);
    }
  } else {
    for (int t = 0; t < CLEN; t++) {
      float dtv = dtp[(size_t)t * DI];
      float uv  = bf2f(up[(size_t)t * DI]);
      float zv  = bf2f(zp[(size_t)t * XZS]);
      float q = dtv * uv;
      float y = 0.f;
      #pragma unroll
      for (int j = 0; j < NST; j++) {
        h[j] = __expf(dtv * av_[j]) * h[j] + q * dblB[t * DBS + j];
        y = fmaf(h[j], dblB[t * DBS + NST + j], y);
      }
      float yv = (y + uv * Dv) * (zv / (1.f + __expf(-zv)));
      ymp[(size_t)t * DI] = f2bf(yv);
    }
  }
}

// ---------------------------------------------------------------------------
extern "C" void kernel_launch(void* const* d_in, const int* in_sizes, int n_in,
                              void* d_out, int out_size, void* d_ws, size_t ws_size,
                              hipStream_t stream) {
  const float* x         = (const float*)d_in[0];
  const float* in_proj_w = (const float*)d_in[1];
  const float* conv_w    = (const float*)d_in[2];
  const float* conv_b    = (const float*)d_in[3];
  const float* x_proj_w  = (const float*)d_in[4];
  const float* dt_proj_w = (const float*)d_in[5];
  const float* dt_proj_b = (const float*)d_in[6];
  const float* A_log     = (const float*)d_in[7];
  const float* D_param   = (const float*)d_in[8];
  const float* out_proj_w= (const float*)d_in[9];
  const float* proj_w    = (const float*)d_in[10];
  const float* proj_b    = (const float*)d_in[11];
  float* out = (float*)d_out;

  // workspace layout (float units)
  float* w = (float*)d_ws;
  float*    mu     = w;                                   // 512
  float*    rstd   = w + 512;                             // 512
  float*    PW     = w + 1024;                            // 73,728
  ushort_t* PW_bf  = (ushort_t*)(w + 74752);              // 256x384 bf16 (49,152 f)
  ushort_t* ipw_bf = (ushort_t*)(w + 123904);             // 768x192 bf16 (73,728 f)
  ushort_t* xpw_bf = (ushort_t*)(w + 197632);             // 128x384 bf16 (24,576 f)
  ushort_t* xT     = (ushort_t*)(w + 222208);             // 6.29M bf16 (3,145,728 f)
  ushort_t* xzT    = (ushort_t*)(w + 3367936);            // 25.2M bf16 (12,582,912 f)
  ushort_t* u_t    = (ushort_t*)(w + 15950848);           // 12.6M bf16 (6,291,456 f)
  float*    dblT   = w + 22242304;                        // 2,097,152 f
  float*    dt_t   = w + 24339456;                        // 12,582,912 f
  ushort_t* ym_t   = (ushort_t*)(w + 36922368);           // 12.6M bf16 (6,291,456 f)
  float*    hend   = w + 43213824;                        // 6,291,456 f
  float*    Pbuf   = w + 49505280;                        // 6,291,456 f
  size_t need = 55796736;
  if (ws_size < need * sizeof(float)) return;

  norm_stats_kernel<<<dim3(BB * CM), dim3(256), 0, stream>>>(x, mu, rstd);
  fuse_proj_kernel<<<dim3((CM * DI + 255) / 256), dim3(256), 0, stream>>>(proj_w, out_proj_w, PW);
  cvt_weights_kernel<<<dim3((2 * DI * CM + 255) / 256), dim3(256), 0, stream>>>(
      in_proj_w, x_proj_w, PW, ipw_bf, xpw_bf, PW_bf);
  xt_norm_kernel<<<dim3(LL / 64, CM / 64, BB), dim3(256), 0, stream>>>(x, mu, rstd, xT);

  // GEMM1: xzT[b][t][768] = xT(BT) x in_proj_w   (M=768 => MT=6, K=192)
  gemm_lds<true, ushort_t><<<dim3(256 * 6), dim3(256), 0, stream>>>(
      ipw_bf, xT, xzT, CM, 768, 6, (long)LL * CM, (long)LL * XZS, XZS, nullptr);

  conv_silu_kernel<<<dim3(LL / CVT, BB), dim3(384), 0, stream>>>(xzT, conv_w, conv_b, u_t);

  // GEMM2: dblT[b][t][64] = u_t(BT) x x_proj_w(padded 128)  (Mreal=64, MT=1, K=384)
  gemm_lds<true, float><<<dim3(256 * 1), dim3(256), 0, stream>>>(
      xpw_bf, u_t, dblT, DI, 64, 1, (long)LL * DI, (long)LL * DBS, DBS, nullptr);

  dt_kernel<<<dim3(LL / DTT, BB), dim3(384), 0, stream>>>(dblT, dt_proj_w, dt_proj_b, dt_t);

  scan_phase1<<<dim3(NC, BB), dim3(384), 0, stream>>>(dt_t, u_t, dblT, A_log, hend, Pbuf);
  scan_combine<<<dim3(BB * DI), dim3(256), 0, stream>>>(hend, Pbuf);
  scan_phase3<<<dim3(NC, BB), dim3(384), 0, stream>>>(dt_t, u_t, dblT, A_log, hend, D_param, xzT, ym_t);

  // GEMM3: out[b][192][L] = PW(padded 256) x ym_t(BT) + proj_b  (Mreal=192, MT=2, K=384)
  gemm_lds<false, float><<<dim3(256 * 2), dim3(256), 0, stream>>>(
      PW_bf, ym_t, out, DI, CM, 2, (long)LL * DI, (long)CM * LL, LL, proj_b);
}

// Round 9
// 200.884 us; speedup vs baseline: 1.3507x; 1.1291x over previous
//
#include <hip/hip_runtime.h>
#include <hip/hip_bf16.h>
#include <math.h>

// Problem constants
#define BB   2
#define CM   192        // D_MODEL
#define DI   384        // D_INNER
#define LL   16384      // D*H*W
#define NST  16         // D_STATE
#define RDT  12         // DT_RANK
#define XJ   44         // DT_RANK + 2*D_STATE
#define NC   512        // scan chunks
#define CLEN 32         // chunk length (NC*CLEN == LL)
#define NCH  (NC / 16)  // chunks per combine-thread
#define DBS  64         // dblT row stride (GEMM2 padded M)
#define XZS  768        // xzT row stride
#define CVT  32         // conv t-tile
#define BK   32         // GEMM k-tile

typedef __attribute__((ext_vector_type(8))) short bf16x8;
typedef __attribute__((ext_vector_type(4))) float f32x4;
typedef unsigned short ushort_t;

static __device__ __forceinline__ ushort_t f2bf(float f) {
  __hip_bfloat16 h = __float2bfloat16(f);
  return *reinterpret_cast<ushort_t*>(&h);
}
static __device__ __forceinline__ float bf2f(ushort_t u) {
  __hip_bfloat16 h;
  *reinterpret_cast<ushort_t*>(&h) = u;
  return __bfloat162float(h);
}

// ---------------------------------------------------------------------------
// PW = proj_w(192x192) @ out_proj_w(192x384)   (fp32, tiny)
__global__ __launch_bounds__(256) void fuse_proj_kernel(
    const float* __restrict__ pw, const float* __restrict__ ow, float* __restrict__ PW) {
  int idx = blockIdx.x * 256 + threadIdx.x;
  if (idx >= CM * DI) return;
  int o = idx / DI, d = idx % DI;
  float s = 0.f;
  #pragma unroll 4
  for (int c = 0; c < CM; c++) s += pw[o * CM + c] * ow[c * DI + d];
  PW[idx] = s;
}

// ---------------------------------------------------------------------------
// Weight conversions to bf16. Row-padding with zeros:
// ipw_bf 768x192 (exact), xpw_bf 128x384 (rows>=44 zero), PW_bf 256x384 (rows>=192 zero)
__global__ __launch_bounds__(256) void cvt_weights_kernel(
    const float* __restrict__ ipw, const float* __restrict__ xpw,
    const float* __restrict__ PW,
    ushort_t* __restrict__ ipw_bf, ushort_t* __restrict__ xpw_bf,
    ushort_t* __restrict__ PW_bf) {
  int i = blockIdx.x * 256 + threadIdx.x;
  if (i < 2 * DI * CM) ipw_bf[i] = f2bf(ipw[i]);
  if (i < 128 * DI) {
    int r = i / DI;
    xpw_bf[i] = (r < XJ) ? f2bf(xpw[i]) : (ushort_t)0;
  }
  if (i < 256 * DI) {
    int r = i / DI;
    PW_bf[i] = (r < CM) ? f2bf(PW[i]) : (ushort_t)0;
  }
}

// ---------------------------------------------------------------------------
// per-(b,c) mean / rstd over L
__global__ __launch_bounds__(256) void norm_stats_kernel(
    const float* __restrict__ x, float* __restrict__ mu, float* __restrict__ rstd) {
  int bc = blockIdx.x;
  const float* p = x + (size_t)bc * LL;
  float s = 0.f, ss = 0.f;
  for (int i = threadIdx.x * 4; i < LL; i += 256 * 4) {
    float4 v = *(const float4*)(p + i);
    s += v.x + v.y + v.z + v.w;
    ss += v.x * v.x + v.y * v.y + v.z * v.z + v.w * v.w;
  }
  for (int o = 32; o > 0; o >>= 1) {
    s += __shfl_down(s, o, 64);
    ss += __shfl_down(ss, o, 64);
  }
  __shared__ float sb[4], ssb[4];
  int wid = threadIdx.x >> 6;
  if ((threadIdx.x & 63) == 0) { sb[wid] = s; ssb[wid] = ss; }
  __syncthreads();
  if (threadIdx.x == 0) {
    s = sb[0] + sb[1] + sb[2] + sb[3];
    ss = ssb[0] + ssb[1] + ssb[2] + ssb[3];
    float m = s * (1.f / LL);
    float var = ss * (1.f / LL) - m * m;
    mu[bc] = m;
    rstd[bc] = 1.f / sqrtf(var + 1e-5f);
  }
}

// ---------------------------------------------------------------------------
// xT[b][t][c] bf16 = normalized x (LDS 64x64 transpose tile)
__global__ __launch_bounds__(256) void xt_norm_kernel(
    const float* __restrict__ x, const float* __restrict__ mu,
    const float* __restrict__ rstd, ushort_t* __restrict__ xT) {
  __shared__ ushort_t T[64][72];
  int t0 = blockIdx.x * 64, c0 = blockIdx.y * 64, b = blockIdx.z;
  int tid = threadIdx.x;
  int c = tid >> 2, tq = (tid & 3) * 16;
  int bc = b * CM + c0 + c;
  const float* xp = x + (size_t)bc * LL + t0 + tq;
  float m = mu[bc], rs = rstd[bc];
  #pragma unroll
  for (int j = 0; j < 16; j += 4) {
    float4 v = *(const float4*)(xp + j);
    T[c][tq + j + 0] = f2bf((v.x - m) * rs);
    T[c][tq + j + 1] = f2bf((v.y - m) * rs);
    T[c][tq + j + 2] = f2bf((v.z - m) * rs);
    T[c][tq + j + 3] = f2bf((v.w - m) * rs);
  }
  __syncthreads();
  int t = tid >> 2, cq = (tid & 3) * 16;
  unsigned int ob[8];
  #pragma unroll
  for (int j = 0; j < 8; j++)
    ob[j] = (unsigned int)T[cq + 2 * j][t] | ((unsigned int)T[cq + 2 * j + 1][t] << 16);
  ushort_t* op = xT + ((size_t)b * LL + t0 + t) * CM + c0 + cq;
  *(uint4*)(op)     = make_uint4(ob[0], ob[1], ob[2], ob[3]);
  *(uint4*)(op + 8) = make_uint4(ob[4], ob[5], ob[6], ob[7]);
}

// ---------------------------------------------------------------------------
// LDS-pipelined MFMA bf16 GEMM (BK=32 double-buffer, global_load_lds).
// A[Mp][K] bf16 row-major, Mp = MT*128 (zero-padded). BT[b][N][K] bf16.
// 1D grid = 256*MT blocks; MT m-tiles of one n-tile co-located on one XCD.
// TOUT=true : C[b][n][m] (ldc = row stride); TOUT=false: C[b][m][n] (+bias[m]).
template <bool TOUT, typename OutT>
__global__ __launch_bounds__(256) void gemm_lds(
    const ushort_t* __restrict__ A, const ushort_t* __restrict__ BT,
    OutT* __restrict__ C, int K, int Mreal, int MT,
    long strideBT, long strideC, int ldc,
    const float* __restrict__ bias) {
  __shared__ ushort_t Asm[2][128 * BK];
  __shared__ ushort_t Bsm[2][128 * BK];

  int id = blockIdx.x;
  int per = MT * 8;
  int g = id / per, r = id % per;
  int nt = g * 8 + (r & 7);
  int mt = r >> 3;
  int b  = nt >> 7;
  long n0 = (long)(nt & 127) * 128;
  int m0 = mt * 128;

  int tid = threadIdx.x;
  int lane = tid & 63, wave = tid >> 6;
  const ushort_t* Bbase = BT + (size_t)b * strideBT;

  int srow0 = wave * 32 + (lane >> 2);
  int sk = (lane & 3) * 8;

  f32x4 acc[4][4];
  #pragma unroll
  for (int mi = 0; mi < 4; mi++)
    #pragma unroll
    for (int ni = 0; ni < 4; ni++) acc[mi][ni] = (f32x4){0.f, 0.f, 0.f, 0.f};

  int mh = wave & 1, nh = wave >> 1;
  int fr = lane & 15, fk = (lane >> 4) * 8;

  int nsteps = K / BK;
  {
    const ushort_t* As0 = A + (size_t)(m0 + srow0) * K + sk;
    const ushort_t* Bs0 = Bbase + (size_t)(n0 + srow0) * K + sk;
    __builtin_amdgcn_global_load_lds(As0, &Asm[0][wave * 1024], 16, 0, 0);
    __builtin_amdgcn_global_load_lds(As0 + (size_t)16 * K, &Asm[0][wave * 1024 + 512], 16, 0, 0);
    __builtin_amdgcn_global_load_lds(Bs0, &Bsm[0][wave * 1024], 16, 0, 0);
    __builtin_amdgcn_global_load_lds(Bs0 + (size_t)16 * K, &Bsm[0][wave * 1024 + 512], 16, 0, 0);
  }
  __syncthreads();
  int cur = 0;
  for (int s = 0; s < nsteps; s++) {
    if (s + 1 < nsteps) {
      int k0 = (s + 1) * BK;
      const ushort_t* As0 = A + (size_t)(m0 + srow0) * K + k0 + sk;
      const ushort_t* Bs0 = Bbase + (size_t)(n0 + srow0) * K + k0 + sk;
      __builtin_amdgcn_global_load_lds(As0, &Asm[cur ^ 1][wave * 1024], 16, 0, 0);
      __builtin_amdgcn_global_load_lds(As0 + (size_t)16 * K, &Asm[cur ^ 1][wave * 1024 + 512], 16, 0, 0);
      __builtin_amdgcn_global_load_lds(Bs0, &Bsm[cur ^ 1][wave * 1024], 16, 0, 0);
      __builtin_amdgcn_global_load_lds(Bs0 + (size_t)16 * K, &Bsm[cur ^ 1][wave * 1024 + 512], 16, 0, 0);
    }
    bf16x8 fa[4], fb[4];
    #pragma unroll
    for (int mi = 0; mi < 4; mi++)
      fa[mi] = *(const bf16x8*)&Asm[cur][(mh * 64 + mi * 16 + fr) * BK + fk];
    #pragma unroll
    for (int ni = 0; ni < 4; ni++)
      fb[ni] = *(const bf16x8*)&Bsm[cur][(nh * 64 + ni * 16 + fr) * BK + fk];
    #pragma unroll
    for (int mi = 0; mi < 4; mi++)
      #pragma unroll
      for (int ni = 0; ni < 4; ni++) {
        if constexpr (TOUT)
          acc[mi][ni] = __builtin_amdgcn_mfma_f32_16x16x32_bf16(fb[ni], fa[mi], acc[mi][ni], 0, 0, 0);
        else
          acc[mi][ni] = __builtin_amdgcn_mfma_f32_16x16x32_bf16(fa[mi], fb[ni], acc[mi][ni], 0, 0, 0);
      }
    __syncthreads();
    cur ^= 1;
  }

  int cq = (lane >> 4) * 4;
  if constexpr (TOUT) {
    #pragma unroll
    for (int ni = 0; ni < 4; ni++)
      #pragma unroll
      for (int rg = 0; rg < 4; rg++) {
        long n = n0 + nh * 64 + ni * 16 + cq + rg;
        OutT* cp = C + (size_t)b * strideC + n * ldc + m0 + mh * 64 + fr;
        #pragma unroll
        for (int mi = 0; mi < 4; mi++) {
          int mrow = m0 + mh * 64 + mi * 16 + fr;
          if (mrow < Mreal) {
            float v = acc[mi][ni][rg];
            if constexpr (sizeof(OutT) == 2) cp[mi * 16] = f2bf(v);
            else                             cp[mi * 16] = v;
          }
        }
      }
  } else {
    #pragma unroll
    for (int mi = 0; mi < 4; mi++)
      #pragma unroll
      for (int rg = 0; rg < 4; rg++) {
        int m = m0 + mh * 64 + mi * 16 + cq + rg;
        if (m < Mreal) {
          float bv = bias ? bias[m] : 0.f;
          OutT* cp = C + (size_t)b * strideC + (size_t)m * ldc + n0 + nh * 64 + fr;
          #pragma unroll
          for (int ni = 0; ni < 4; ni++)
            cp[ni * 16] = acc[mi][ni][rg] + bv;
        }
      }
  }
}

// ---------------------------------------------------------------------------
// Conv: causal depthwise k=4 + bias + SiLU.
__global__ __launch_bounds__(384) void conv_silu_kernel(
    const ushort_t* __restrict__ xzT, const float* __restrict__ conv_w,
    const float* __restrict__ conv_b, ushort_t* __restrict__ u_t) {
  __shared__ ushort_t Us[CVT + 3][DI];
  int t0 = blockIdx.x * CVT;
  int b = blockIdx.y;
  int tid = threadIdx.x;
  #pragma unroll
  for (int r = 0; r < CVT + 3; r++) {
    int t = t0 - 3 + r;
    Us[r][tid] = (t >= 0) ? xzT[((size_t)b * LL + t) * XZS + tid] : (ushort_t)0;
  }
  float w0 = conv_w[tid * 4 + 0], w1 = conv_w[tid * 4 + 1];
  float w2 = conv_w[tid * 4 + 2], w3 = conv_w[tid * 4 + 3];
  float cb = conv_b[tid];
  __syncthreads();
  ushort_t* up = u_t + ((size_t)b * LL + t0) * DI + tid;
  float xm3 = bf2f(Us[0][tid]);
  float xm2 = bf2f(Us[1][tid]);
  float xm1 = bf2f(Us[2][tid]);
  #pragma unroll
  for (int t = 0; t < CVT; t++) {
    float xc = bf2f(Us[t + 3][tid]);
    float a = cb + w3 * xc + w2 * xm1 + w1 * xm2 + w0 * xm3;
    float sv = a / (1.f + __expf(-a));
    up[(size_t)t * DI] = f2bf(sv);
    xm3 = xm2; xm2 = xm1; xm1 = xc;
  }
}

// ---------------------------------------------------------------------------
// Scan phase 1 (dt fused): block=(chunk,b), 384 thr = 1 per channel d.
// dt = softplus(dtw[d] . dbl_low[t] + dtb[d]) computed inline from uniform
// scalar loads. Stores hend (16 floats) + S = sum(dt) per (bd,chunk).
__global__ __launch_bounds__(384) void scan_phase1(
    const ushort_t* __restrict__ u_t, const float* __restrict__ dblT,
    const float* __restrict__ A_log,
    const float* __restrict__ dtw, const float* __restrict__ dtb,
    float* __restrict__ hend, float* __restrict__ Sbuf) {
  int tid = threadIdx.x;
  int chunk = blockIdx.x, b = blockIdx.y;
  int t0 = chunk * CLEN;
  const float* dblB = dblT + ((size_t)b * LL + t0) * DBS;  // uniform base
  int d = tid;
  int bd = b * DI + d;
  float av0 = -expf(A_log[d * NST]);
  float av_[NST];
  bool ok = true;
  #pragma unroll
  for (int j = 0; j < NST; j++) {
    av_[j] = -expf(A_log[d * NST + j]);
    ok = ok && (fabsf(av_[j] - av0 * (float)(j + 1)) <= 1e-4f * fabsf(av_[j]));
  }
  float w12[12];
  #pragma unroll
  for (int rr = 0; rr < 12; rr += 4)
    *(float4*)(w12 + rr) = *(const float4*)(dtw + d * 12 + rr);
  float db = dtb[d];
  const ushort_t* up = u_t + ((size_t)b * LL + t0) * DI + d;
  float h[NST];
  #pragma unroll
  for (int j = 0; j < NST; j++) h[j] = 0.f;
  float S = 0.f;

  size_t o = ((size_t)bd * NC + chunk) * NST;
  if (__all(ok)) {
    #pragma unroll 2
    for (int t = 0; t < CLEN; t++) {
      float4 L0 = *(const float4*)(dblB + t * DBS + 0);
      float4 L1 = *(const float4*)(dblB + t * DBS + 4);
      float4 L2 = *(const float4*)(dblB + t * DBS + 8);
      float4 B0 = *(const float4*)(dblB + t * DBS + RDT + 0);
      float4 B1 = *(const float4*)(dblB + t * DBS + RDT + 4);
      float4 B2 = *(const float4*)(dblB + t * DBS + RDT + 8);
      float4 B3 = *(const float4*)(dblB + t * DBS + RDT + 12);
      float acc = db;
      acc = fmaf(L0.x, w12[0], acc); acc = fmaf(L0.y, w12[1], acc);
      acc = fmaf(L0.z, w12[2], acc); acc = fmaf(L0.w, w12[3], acc);
      acc = fmaf(L1.x, w12[4], acc); acc = fmaf(L1.y, w12[5], acc);
      acc = fmaf(L1.z, w12[6], acc); acc = fmaf(L1.w, w12[7], acc);
      acc = fmaf(L2.x, w12[8], acc); acc = fmaf(L2.y, w12[9], acc);
      acc = fmaf(L2.z, w12[10], acc); acc = fmaf(L2.w, w12[11], acc);
      float dtv = (acc > 15.f) ? acc : __logf(1.f + __expf(acc));
      float uv  = bf2f(up[(size_t)t * DI]);
      float q = dtv * uv;
      S += dtv;
      float p1 = __expf(dtv * av0);
      float p2 = p1 * p1, p4 = p2 * p2, p8 = p4 * p4;
      float p3 = p2 * p1, p5 = p4 * p1, p6 = p4 * p2, p7 = p4 * p3;
      h[0]  = fmaf(p1, h[0],  q * B0.x);
      h[1]  = fmaf(p2, h[1],  q * B0.y);
      h[2]  = fmaf(p3, h[2],  q * B0.z);
      h[3]  = fmaf(p4, h[3],  q * B0.w);
      h[4]  = fmaf(p5, h[4],  q * B1.x);
      h[5]  = fmaf(p6, h[5],  q * B1.y);
      h[6]  = fmaf(p7, h[6],  q * B1.z);
      h[7]  = fmaf(p8, h[7],  q * B1.w);
      h[8]  = fmaf(p8 * p1, h[8],  q * B2.x);
      h[9]  = fmaf(p8 * p2, h[9],  q * B2.y);
      h[10] = fmaf(p8 * p3, h[10], q * B2.z);
      h[11] = fmaf(p8 * p4, h[11], q * B2.w);
      h[12] = fmaf(p8 * p5, h[12], q * B3.x);
      h[13] = fmaf(p8 * p6, h[13], q * B3.y);
      h[14] = fmaf(p8 * p7, h[14], q * B3.z);
      h[15] = fmaf(p8 * p8, h[15], q * B3.w);
    }
  } else {
    for (int t = 0; t < CLEN; t++) {
      float acc = db;
      #pragma unroll
      for (int rr = 0; rr < 12; rr++) acc = fmaf(dblB[t * DBS + rr], w12[rr], acc);
      float dtv = (acc > 15.f) ? acc : __logf(1.f + __expf(acc));
      float uv  = bf2f(up[(size_t)t * DI]);
      float q = dtv * uv;
      S += dtv;
      #pragma unroll
      for (int j = 0; j < NST; j++)
        h[j] = __expf(dtv * av_[j]) * h[j] + q * dblB[t * DBS + RDT + j];
    }
  }
  #pragma unroll
  for (int j = 0; j < NST; j += 4)
    *(float4*)(hend + o + j) = make_float4(h[j], h[j+1], h[j+2], h[j+3]);
  Sbuf[(size_t)bd * NC + chunk] = S;
}

// ---------------------------------------------------------------------------
// Scan combine: block per bd (768 blocks), 256 thr = (g=tid>>4, s=tid&15).
// Decay products reconstructed as exp(S * av_s) from Sbuf (1 float/chunk).
__global__ __launch_bounds__(256) void scan_combine(
    float* __restrict__ hend, const float* __restrict__ Sbuf,
    const float* __restrict__ A_log) {
  __shared__ float sP[16][16], sH[16][16];
  int bd = blockIdx.x;
  int d = bd % DI;
  int s = threadIdx.x & 15, g = threadIdx.x >> 4;
  float av = -expf(A_log[d * NST + s]);
  size_t baseS = (size_t)bd * NC + g * NCH;
  size_t base = ((size_t)bd * NC + g * NCH) * NST + s;
  float Pl = 1.f, Hl = 0.f;
  #pragma unroll
  for (int k = 0; k < NCH; k++) {
    float p = __expf(Sbuf[baseS + k] * av);
    Hl = fmaf(p, Hl, hend[base + (size_t)k * NST]);
    Pl *= p;
  }
  sP[g][s] = Pl; sH[g][s] = Hl;
  __syncthreads();
  if (threadIdx.x < 16) {
    int ss = threadIdx.x;
    float c = 0.f;
    #pragma unroll
    for (int gg = 0; gg < 16; gg++) {
      float tmp = sH[gg][ss];
      float pp  = sP[gg][ss];
      sH[gg][ss] = c;
      c = fmaf(pp, c, tmp);
    }
  }
  __syncthreads();
  float c = sH[g][s];
  #pragma unroll
  for (int k = 0; k < NCH; k++) {
    size_t o = base + (size_t)k * NST;
    float p = __expf(Sbuf[baseS + k] * av);
    float he = hend[o];
    hend[o] = c;
    c = fmaf(p, c, he);
  }
}

// ---------------------------------------------------------------------------
// Scan phase 3 (dt fused): replay with carry; ym = (y + u*D) * silu(z).
__global__ __launch_bounds__(384) void scan_phase3(
    const ushort_t* __restrict__ u_t, const float* __restrict__ dblT,
    const float* __restrict__ A_log,
    const float* __restrict__ dtw, const float* __restrict__ dtb,
    const float* __restrict__ hin, const float* __restrict__ Dp,
    const ushort_t* __restrict__ xzT, ushort_t* __restrict__ ym_t) {
  int tid = threadIdx.x;
  int chunk = blockIdx.x, b = blockIdx.y;
  int t0 = chunk * CLEN;
  const float* dblB = dblT + ((size_t)b * LL + t0) * DBS;  // uniform base
  int d = tid;
  int bd = b * DI + d;
  float av0 = -expf(A_log[d * NST]);
  float av_[NST];
  bool ok = true;
  #pragma unroll
  for (int j = 0; j < NST; j++) {
    av_[j] = -expf(A_log[d * NST + j]);
    ok = ok && (fabsf(av_[j] - av0 * (float)(j + 1)) <= 1e-4f * fabsf(av_[j]));
  }
  float w12[12];
  #pragma unroll
  for (int rr = 0; rr < 12; rr += 4)
    *(float4*)(w12 + rr) = *(const float4*)(dtw + d * 12 + rr);
  float db = dtb[d];
  const ushort_t* up = u_t + ((size_t)b * LL + t0) * DI + d;
  const ushort_t* zp = xzT + ((size_t)b * LL + t0) * XZS + DI + d;
  ushort_t* ymp = ym_t + ((size_t)b * LL + t0) * DI + d;

  float h[NST];
  const float* hi = hin + ((size_t)bd * NC + chunk) * NST;
  #pragma unroll
  for (int j = 0; j < NST; j += 4) {
    float4 v = *(const float4*)(hi + j);
    h[j] = v.x; h[j+1] = v.y; h[j+2] = v.z; h[j+3] = v.w;
  }
  float Dv = Dp[d];

  if (__all(ok)) {
    #pragma unroll 2
    for (int t = 0; t < CLEN; t++) {
      float4 L0 = *(const float4*)(dblB + t * DBS + 0);
      float4 L1 = *(const float4*)(dblB + t * DBS + 4);
      float4 L2 = *(const float4*)(dblB + t * DBS + 8);
      float4 B0 = *(const float4*)(dblB + t * DBS + RDT + 0);
      float4 B1 = *(const float4*)(dblB + t * DBS + RDT + 4);
      float4 B2 = *(const float4*)(dblB + t * DBS + RDT + 8);
      float4 B3 = *(const float4*)(dblB + t * DBS + RDT + 12);
      float4 C0 = *(const float4*)(dblB + t * DBS + RDT + 16);
      float4 C1 = *(const float4*)(dblB + t * DBS + RDT + 20);
      float4 C2 = *(const float4*)(dblB + t * DBS + RDT + 24);
      float4 C3 = *(const float4*)(dblB + t * DBS + RDT + 28);
      float acc = db;
      acc = fmaf(L0.x, w12[0], acc); acc = fmaf(L0.y, w12[1], acc);
      acc = fmaf(L0.z, w12[2], acc); acc = fmaf(L0.w, w12[3], acc);
      acc = fmaf(L1.x, w12[4], acc); acc = fmaf(L1.y, w12[5], acc);
      acc = fmaf(L1.z, w12[6], acc); acc = fmaf(L1.w, w12[7], acc);
      acc = fmaf(L2.x, w12[8], acc); acc = fmaf(L2.y, w12[9], acc);
      acc = fmaf(L2.z, w12[10], acc); acc = fmaf(L2.w, w12[11], acc);
      float dtv = (acc > 15.f) ? acc : __logf(1.f + __expf(acc));
      float uv  = bf2f(up[(size_t)t * DI]);
      float zv  = bf2f(zp[(size_t)t * XZS]);
      float q = dtv * uv;
      float p1 = __expf(dtv * av0);
      float p2 = p1 * p1, p4 = p2 * p2, p8 = p4 * p4;
      float p3 = p2 * p1, p5 = p4 * p1, p6 = p4 * p2, p7 = p4 * p3;
      float y0, y1, y2, y3;
      h[0]  = fmaf(p1, h[0],  q * B0.x); y0 = h[0] * C0.x;
      h[1]  = fmaf(p2, h[1],  q * B0.y); y1 = h[1] * C0.y;
      h[2]  = fmaf(p3, h[2],  q * B0.z); y2 = h[2] * C0.z;
      h[3]  = fmaf(p4, h[3],  q * B0.w); y3 = h[3] * C0.w;
      h[4]  = fmaf(p5, h[4],  q * B1.x); y0 = fmaf(h[4],  C1.x, y0);
      h[5]  = fmaf(p6, h[5],  q * B1.y); y1 = fmaf(h[5],  C1.y, y1);
      h[6]  = fmaf(p7, h[6],  q * B1.z); y2 = fmaf(h[6],  C1.z, y2);
      h[7]  = fmaf(p8, h[7],  q * B1.w); y3 = fmaf(h[7],  C1.w, y3);
      h[8]  = fmaf(p8 * p1, h[8],  q * B2.x); y0 = fmaf(h[8],  C2.x, y0);
      h[9]  = fmaf(p8 * p2, h[9],  q * B2.y); y1 = fmaf(h[9],  C2.y, y1);
      h[10] = fmaf(p8 * p3, h[10], q * B2.z); y2 = fmaf(h[10], C2.z, y2);
      h[11] = fmaf(p8 * p4, h[11], q * B2.w); y3 = fmaf(h[11], C2.w, y3);
      h[12] = fmaf(p8 * p5, h[12], q * B3.x); y0 = fmaf(h[12], C3.x, y0);
      h[13] = fmaf(p8 * p6, h[13], q * B3.y); y1 = fmaf(h[13], C3.y, y1);
      h[14] = fmaf(p8 * p7, h[14], q * B3.z); y2 = fmaf(h[14], C3.z, y2);
      h[15] = fmaf(p8 * p8, h[15], q * B3.w); y3 = fmaf(h[15], C3.w, y3);
      float y = (y0 + y1) + (y2 + y3);
      float yv = (y + uv * Dv) * (zv / (1.f + __expf(-zv)));
      ymp[(size_t)t * DI] = f2bf(yv);
    }
  } else {
    for (int t = 0; t < CLEN; t++) {
      float acc = db;
      #pragma unroll
      for (int rr = 0; rr < 12; rr++) acc = fmaf(dblB[t * DBS + rr], w12[rr], acc);
      float dtv = (acc > 15.f) ? acc : __logf(1.f + __expf(acc));
      float uv  = bf2f(up[(size_t)t * DI]);
      float zv  = bf2f(zp[(size_t)t * XZS]);
      float q = dtv * uv;
      float y = 0.f;
      #pragma unroll
      for (int j = 0; j < NST; j++) {
        h[j] = __expf(dtv * av_[j]) * h[j] + q * dblB[t * DBS + RDT + j];
        y = fmaf(h[j], dblB[t * DBS + RDT + NST + j], y);
      }
      float yv = (y + uv * Dv) * (zv / (1.f + __expf(-zv)));
      ymp[(size_t)t * DI] = f2bf(yv);
    }
  }
}

// ---------------------------------------------------------------------------
extern "C" void kernel_launch(void* const* d_in, const int* in_sizes, int n_in,
                              void* d_out, int out_size, void* d_ws, size_t ws_size,
                              hipStream_t stream) {
  const float* x         = (const float*)d_in[0];
  const float* in_proj_w = (const float*)d_in[1];
  const float* conv_w    = (const float*)d_in[2];
  const float* conv_b    = (const float*)d_in[3];
  const float* x_proj_w  = (const float*)d_in[4];
  const float* dt_proj_w = (const float*)d_in[5];
  const float* dt_proj_b = (const float*)d_in[6];
  const float* A_log     = (const float*)d_in[7];
  const float* D_param   = (const float*)d_in[8];
  const float* out_proj_w= (const float*)d_in[9];
  const float* proj_w    = (const float*)d_in[10];
  const float* proj_b    = (const float*)d_in[11];
  float* out = (float*)d_out;

  // workspace layout (float units)
  float* w = (float*)d_ws;
  float*    mu     = w;                                   // 512
  float*    rstd   = w + 512;                             // 512
  float*    PW     = w + 1024;                            // 73,728
  ushort_t* PW_bf  = (ushort_t*)(w + 74752);              // 256x384 bf16 (49,152 f)
  ushort_t* ipw_bf = (ushort_t*)(w + 123904);             // 768x192 bf16 (73,728 f)
  ushort_t* xpw_bf = (ushort_t*)(w + 197632);             // 128x384 bf16 (24,576 f)
  ushort_t* xT     = (ushort_t*)(w + 222208);             // 6.29M bf16 (3,145,728 f)
  ushort_t* xzT    = (ushort_t*)(w + 3367936);            // 25.2M bf16 (12,582,912 f)
  ushort_t* u_t    = (ushort_t*)(w + 15950848);           // 12.6M bf16 (6,291,456 f)
  float*    dblT   = w + 22242304;                        // 2,097,152 f
  ushort_t* ym_t   = (ushort_t*)(w + 24339456);           // 12.6M bf16 (6,291,456 f)
  float*    hend   = w + 30630912;                        // 6,291,456 f
  float*    Sbuf   = w + 36922368;                        // 393,216 f
  size_t need = 37315584;
  if (ws_size < need * sizeof(float)) return;

  norm_stats_kernel<<<dim3(BB * CM), dim3(256), 0, stream>>>(x, mu, rstd);
  fuse_proj_kernel<<<dim3((CM * DI + 255) / 256), dim3(256), 0, stream>>>(proj_w, out_proj_w, PW);
  cvt_weights_kernel<<<dim3((2 * DI * CM + 255) / 256), dim3(256), 0, stream>>>(
      in_proj_w, x_proj_w, PW, ipw_bf, xpw_bf, PW_bf);
  xt_norm_kernel<<<dim3(LL / 64, CM / 64, BB), dim3(256), 0, stream>>>(x, mu, rstd, xT);

  // GEMM1: xzT[b][t][768] = xT(BT) x in_proj_w   (M=768 => MT=6, K=192)
  gemm_lds<true, ushort_t><<<dim3(256 * 6), dim3(256), 0, stream>>>(
      ipw_bf, xT, xzT, CM, 768, 6, (long)LL * CM, (long)LL * XZS, XZS, nullptr);

  conv_silu_kernel<<<dim3(LL / CVT, BB), dim3(384), 0, stream>>>(xzT, conv_w, conv_b, u_t);

  // GEMM2: dblT[b][t][64] = u_t(BT) x x_proj_w(padded 128)  (Mreal=64, MT=1, K=384)
  gemm_lds<true, float><<<dim3(256 * 1), dim3(256), 0, stream>>>(
      xpw_bf, u_t, dblT, DI, 64, 1, (long)LL * DI, (long)LL * DBS, DBS, nullptr);

  scan_phase1<<<dim3(NC, BB), dim3(384), 0, stream>>>(
      u_t, dblT, A_log, dt_proj_w, dt_proj_b, hend, Sbuf);
  scan_combine<<<dim3(BB * DI), dim3(256), 0, stream>>>(hend, Sbuf, A_log);
  scan_phase3<<<dim3(NC, BB), dim3(384), 0, stream>>>(
      u_t, dblT, A_log, dt_proj_w, dt_proj_b, hend, D_param, xzT, ym_t);

  // GEMM3: out[b][192][L] = PW(padded 256) x ym_t(BT) + proj_b  (Mreal=192, MT=2, K=384)
  gemm_lds<false, float><<<dim3(256 * 2), dim3(256), 0, stream>>>(
      PW_bf, ym_t, out, DI, CM, 2, (long)LL * DI, (long)CM * LL, LL, proj_b);
}

// Round 10
// 191.766 us; speedup vs baseline: 1.4150x; 1.0476x over previous
//
#include <hip/hip_runtime.h>
#include <hip/hip_bf16.h>
#include <hip/hip_fp16.h>
#include <math.h>

// Problem constants
#define BB   2
#define CM   192        // D_MODEL
#define DI   384        // D_INNER
#define LL   16384      // D*H*W
#define NST  16         // D_STATE
#define RDT  12         // DT_RANK
#define XJ   44         // DT_RANK + 2*D_STATE
#define NC   512        // scan chunks
#define CLEN 32         // chunk length (NC*CLEN == LL)
#define NCH  (NC / 16)  // chunks per combine-thread
#define DBS  64         // dblT row stride (GEMM2 padded M)
#define XZS  768        // xzT row stride
#define CVT  32         // conv t-tile
#define BK   32         // GEMM k-tile

typedef __attribute__((ext_vector_type(8))) short bf16x8;
typedef __attribute__((ext_vector_type(4))) float f32x4;
typedef __attribute__((ext_vector_type(2))) float f32x2;
typedef unsigned short ushort_t;

static __device__ __forceinline__ ushort_t f2bf(float f) {
  __hip_bfloat16 h = __float2bfloat16(f);
  return *reinterpret_cast<ushort_t*>(&h);
}
static __device__ __forceinline__ float bf2f(ushort_t u) {
  __hip_bfloat16 h;
  *reinterpret_cast<ushort_t*>(&h) = u;
  return __bfloat162float(h);
}
static __device__ __forceinline__ ushort_t f2h(float f) {
  __half h = __float2half(f);
  return *reinterpret_cast<ushort_t*>(&h);
}
static __device__ __forceinline__ float h2f(ushort_t u) {
  __half h;
  *reinterpret_cast<ushort_t*>(&h) = u;
  return __half2float(h);
}

// ---------------------------------------------------------------------------
// PW = proj_w(192x192) @ out_proj_w(192x384)   (fp32, tiny)
__global__ __launch_bounds__(256) void fuse_proj_kernel(
    const float* __restrict__ pw, const float* __restrict__ ow, float* __restrict__ PW) {
  int idx = blockIdx.x * 256 + threadIdx.x;
  if (idx >= CM * DI) return;
  int o = idx / DI, d = idx % DI;
  float s = 0.f;
  #pragma unroll 4
  for (int c = 0; c < CM; c++) s += pw[o * CM + c] * ow[c * DI + d];
  PW[idx] = s;
}

// ---------------------------------------------------------------------------
// Weight conversions to bf16. Row-padding with zeros.
__global__ __launch_bounds__(256) void cvt_weights_kernel(
    const float* __restrict__ ipw, const float* __restrict__ xpw,
    const float* __restrict__ PW,
    ushort_t* __restrict__ ipw_bf, ushort_t* __restrict__ xpw_bf,
    ushort_t* __restrict__ PW_bf) {
  int i = blockIdx.x * 256 + threadIdx.x;
  if (i < 2 * DI * CM) ipw_bf[i] = f2bf(ipw[i]);
  if (i < 128 * DI) {
    int r = i / DI;
    xpw_bf[i] = (r < XJ) ? f2bf(xpw[i]) : (ushort_t)0;
  }
  if (i < 256 * DI) {
    int r = i / DI;
    PW_bf[i] = (r < CM) ? f2bf(PW[i]) : (ushort_t)0;
  }
}

// ---------------------------------------------------------------------------
// per-(b,c) mean / rstd over L
__global__ __launch_bounds__(256) void norm_stats_kernel(
    const float* __restrict__ x, float* __restrict__ mu, float* __restrict__ rstd) {
  int bc = blockIdx.x;
  const float* p = x + (size_t)bc * LL;
  float s = 0.f, ss = 0.f;
  for (int i = threadIdx.x * 4; i < LL; i += 256 * 4) {
    float4 v = *(const float4*)(p + i);
    s += v.x + v.y + v.z + v.w;
    ss += v.x * v.x + v.y * v.y + v.z * v.z + v.w * v.w;
  }
  for (int o = 32; o > 0; o >>= 1) {
    s += __shfl_down(s, o, 64);
    ss += __shfl_down(ss, o, 64);
  }
  __shared__ float sb[4], ssb[4];
  int wid = threadIdx.x >> 6;
  if ((threadIdx.x & 63) == 0) { sb[wid] = s; ssb[wid] = ss; }
  __syncthreads();
  if (threadIdx.x == 0) {
    s = sb[0] + sb[1] + sb[2] + sb[3];
    ss = ssb[0] + ssb[1] + ssb[2] + ssb[3];
    float m = s * (1.f / LL);
    float var = ss * (1.f / LL) - m * m;
    mu[bc] = m;
    rstd[bc] = 1.f / sqrtf(var + 1e-5f);
  }
}

// ---------------------------------------------------------------------------
// xT[b][t][c] bf16 = normalized x (LDS 64x64 transpose tile)
__global__ __launch_bounds__(256) void xt_norm_kernel(
    const float* __restrict__ x, const float* __restrict__ mu,
    const float* __restrict__ rstd, ushort_t* __restrict__ xT) {
  __shared__ ushort_t T[64][72];
  int t0 = blockIdx.x * 64, c0 = blockIdx.y * 64, b = blockIdx.z;
  int tid = threadIdx.x;
  int c = tid >> 2, tq = (tid & 3) * 16;
  int bc = b * CM + c0 + c;
  const float* xp = x + (size_t)bc * LL + t0 + tq;
  float m = mu[bc], rs = rstd[bc];
  #pragma unroll
  for (int j = 0; j < 16; j += 4) {
    float4 v = *(const float4*)(xp + j);
    T[c][tq + j + 0] = f2bf((v.x - m) * rs);
    T[c][tq + j + 1] = f2bf((v.y - m) * rs);
    T[c][tq + j + 2] = f2bf((v.z - m) * rs);
    T[c][tq + j + 3] = f2bf((v.w - m) * rs);
  }
  __syncthreads();
  int t = tid >> 2, cq = (tid & 3) * 16;
  unsigned int ob[8];
  #pragma unroll
  for (int j = 0; j < 8; j++)
    ob[j] = (unsigned int)T[cq + 2 * j][t] | ((unsigned int)T[cq + 2 * j + 1][t] << 16);
  ushort_t* op = xT + ((size_t)b * LL + t0 + t) * CM + c0 + cq;
  *(uint4*)(op)     = make_uint4(ob[0], ob[1], ob[2], ob[3]);
  *(uint4*)(op + 8) = make_uint4(ob[4], ob[5], ob[6], ob[7]);
}

// ---------------------------------------------------------------------------
// LDS-pipelined MFMA bf16 GEMM (BK=32 double-buffer, global_load_lds).
template <bool TOUT, typename OutT>
__global__ __launch_bounds__(256) void gemm_lds(
    const ushort_t* __restrict__ A, const ushort_t* __restrict__ BT,
    OutT* __restrict__ C, int K, int Mreal, int MT,
    long strideBT, long strideC, int ldc,
    const float* __restrict__ bias) {
  __shared__ ushort_t Asm[2][128 * BK];
  __shared__ ushort_t Bsm[2][128 * BK];

  int id = blockIdx.x;
  int per = MT * 8;
  int g = id / per, r = id % per;
  int nt = g * 8 + (r & 7);
  int mt = r >> 3;
  int b  = nt >> 7;
  long n0 = (long)(nt & 127) * 128;
  int m0 = mt * 128;

  int tid = threadIdx.x;
  int lane = tid & 63, wave = tid >> 6;
  const ushort_t* Bbase = BT + (size_t)b * strideBT;

  int srow0 = wave * 32 + (lane >> 2);
  int sk = (lane & 3) * 8;

  f32x4 acc[4][4];
  #pragma unroll
  for (int mi = 0; mi < 4; mi++)
    #pragma unroll
    for (int ni = 0; ni < 4; ni++) acc[mi][ni] = (f32x4){0.f, 0.f, 0.f, 0.f};

  int mh = wave & 1, nh = wave >> 1;
  int fr = lane & 15, fk = (lane >> 4) * 8;

  int nsteps = K / BK;
  {
    const ushort_t* As0 = A + (size_t)(m0 + srow0) * K + sk;
    const ushort_t* Bs0 = Bbase + (size_t)(n0 + srow0) * K + sk;
    __builtin_amdgcn_global_load_lds(As0, &Asm[0][wave * 1024], 16, 0, 0);
    __builtin_amdgcn_global_load_lds(As0 + (size_t)16 * K, &Asm[0][wave * 1024 + 512], 16, 0, 0);
    __builtin_amdgcn_global_load_lds(Bs0, &Bsm[0][wave * 1024], 16, 0, 0);
    __builtin_amdgcn_global_load_lds(Bs0 + (size_t)16 * K, &Bsm[0][wave * 1024 + 512], 16, 0, 0);
  }
  __syncthreads();
  int cur = 0;
  for (int s = 0; s < nsteps; s++) {
    if (s + 1 < nsteps) {
      int k0 = (s + 1) * BK;
      const ushort_t* As0 = A + (size_t)(m0 + srow0) * K + k0 + sk;
      const ushort_t* Bs0 = Bbase + (size_t)(n0 + srow0) * K + k0 + sk;
      __builtin_amdgcn_global_load_lds(As0, &Asm[cur ^ 1][wave * 1024], 16, 0, 0);
      __builtin_amdgcn_global_load_lds(As0 + (size_t)16 * K, &Asm[cur ^ 1][wave * 1024 + 512], 16, 0, 0);
      __builtin_amdgcn_global_load_lds(Bs0, &Bsm[cur ^ 1][wave * 1024], 16, 0, 0);
      __builtin_amdgcn_global_load_lds(Bs0 + (size_t)16 * K, &Bsm[cur ^ 1][wave * 1024 + 512], 16, 0, 0);
    }
    bf16x8 fa[4], fb[4];
    #pragma unroll
    for (int mi = 0; mi < 4; mi++)
      fa[mi] = *(const bf16x8*)&Asm[cur][(mh * 64 + mi * 16 + fr) * BK + fk];
    #pragma unroll
    for (int ni = 0; ni < 4; ni++)
      fb[ni] = *(const bf16x8*)&Bsm[cur][(nh * 64 + ni * 16 + fr) * BK + fk];
    #pragma unroll
    for (int mi = 0; mi < 4; mi++)
      #pragma unroll
      for (int ni = 0; ni < 4; ni++) {
        if constexpr (TOUT)
          acc[mi][ni] = __builtin_amdgcn_mfma_f32_16x16x32_bf16(fb[ni], fa[mi], acc[mi][ni], 0, 0, 0);
        else
          acc[mi][ni] = __builtin_amdgcn_mfma_f32_16x16x32_bf16(fa[mi], fb[ni], acc[mi][ni], 0, 0, 0);
      }
    __syncthreads();
    cur ^= 1;
  }

  int cq = (lane >> 4) * 4;
  if constexpr (TOUT) {
    #pragma unroll
    for (int ni = 0; ni < 4; ni++)
      #pragma unroll
      for (int rg = 0; rg < 4; rg++) {
        long n = n0 + nh * 64 + ni * 16 + cq + rg;
        OutT* cp = C + (size_t)b * strideC + n * ldc + m0 + mh * 64 + fr;
        #pragma unroll
        for (int mi = 0; mi < 4; mi++) {
          int mrow = m0 + mh * 64 + mi * 16 + fr;
          if (mrow < Mreal) {
            float v = acc[mi][ni][rg];
            if constexpr (sizeof(OutT) == 2) cp[mi * 16] = f2bf(v);
            else                             cp[mi * 16] = v;
          }
        }
      }
  } else {
    #pragma unroll
    for (int mi = 0; mi < 4; mi++)
      #pragma unroll
      for (int rg = 0; rg < 4; rg++) {
        int m = m0 + mh * 64 + mi * 16 + cq + rg;
        if (m < Mreal) {
          float bv = bias ? bias[m] : 0.f;
          OutT* cp = C + (size_t)b * strideC + (size_t)m * ldc + n0 + nh * 64 + fr;
          #pragma unroll
          for (int ni = 0; ni < 4; ni++)
            cp[ni * 16] = acc[mi][ni][rg] + bv;
        }
      }
  }
}

// ---------------------------------------------------------------------------
// Conv: causal depthwise k=4 + bias + SiLU.
__global__ __launch_bounds__(384) void conv_silu_kernel(
    const ushort_t* __restrict__ xzT, const float* __restrict__ conv_w,
    const float* __restrict__ conv_b, ushort_t* __restrict__ u_t) {
  __shared__ ushort_t Us[CVT + 3][DI];
  int t0 = blockIdx.x * CVT;
  int b = blockIdx.y;
  int tid = threadIdx.x;
  #pragma unroll
  for (int r = 0; r < CVT + 3; r++) {
    int t = t0 - 3 + r;
    Us[r][tid] = (t >= 0) ? xzT[((size_t)b * LL + t) * XZS + tid] : (ushort_t)0;
  }
  float w0 = conv_w[tid * 4 + 0], w1 = conv_w[tid * 4 + 1];
  float w2 = conv_w[tid * 4 + 2], w3 = conv_w[tid * 4 + 3];
  float cb = conv_b[tid];
  __syncthreads();
  ushort_t* up = u_t + ((size_t)b * LL + t0) * DI + tid;
  float xm3 = bf2f(Us[0][tid]);
  float xm2 = bf2f(Us[1][tid]);
  float xm1 = bf2f(Us[2][tid]);
  #pragma unroll
  for (int t = 0; t < CVT; t++) {
    float xc = bf2f(Us[t + 3][tid]);
    float a = cb + w3 * xc + w2 * xm1 + w1 * xm2 + w0 * xm3;
    float sv = a / (1.f + __expf(-a));
    up[(size_t)t * DI] = f2bf(sv);
    xm3 = xm2; xm2 = xm1; xm1 = xc;
  }
}

// ---------------------------------------------------------------------------
// Scan phase 1 (dt fused, packed fp32 state update).
// Stores hend (16f), S = sum(dt), and dt as fp16 for phase 3.
__global__ __launch_bounds__(384) void scan_phase1(
    const ushort_t* __restrict__ u_t, const float* __restrict__ dblT,
    const float* __restrict__ A_log,
    const float* __restrict__ dtw, const float* __restrict__ dtb,
    float* __restrict__ hend, float* __restrict__ Sbuf,
    ushort_t* __restrict__ dt16) {
  int tid = threadIdx.x;
  int chunk = blockIdx.x, b = blockIdx.y;
  int t0 = chunk * CLEN;
  const float* dblB = dblT + ((size_t)b * LL + t0) * DBS;  // uniform base
  int d = tid;
  int bd = b * DI + d;
  float av0 = -expf(A_log[d * NST]);
  float av_[NST];
  bool ok = true;
  #pragma unroll
  for (int j = 0; j < NST; j++) {
    av_[j] = -expf(A_log[d * NST + j]);
    ok = ok && (fabsf(av_[j] - av0 * (float)(j + 1)) <= 1e-4f * fabsf(av_[j]));
  }
  float w12[12];
  #pragma unroll
  for (int rr = 0; rr < 12; rr += 4)
    *(float4*)(w12 + rr) = *(const float4*)(dtw + d * 12 + rr);
  float db = dtb[d];
  const ushort_t* up = u_t + ((size_t)b * LL + t0) * DI + d;
  ushort_t* dtp16 = dt16 + ((size_t)b * LL + t0) * DI + d;
  float S = 0.f;

  size_t o = ((size_t)bd * NC + chunk) * NST;
  if (__all(ok)) {
    f32x2 h2[8];
    #pragma unroll
    for (int j = 0; j < 8; j++) h2[j] = (f32x2){0.f, 0.f};
    #pragma unroll 2
    for (int t = 0; t < CLEN; t++) {
      float4 L0 = *(const float4*)(dblB + t * DBS + 0);
      float4 L1 = *(const float4*)(dblB + t * DBS + 4);
      float4 L2 = *(const float4*)(dblB + t * DBS + 8);
      float4 B0 = *(const float4*)(dblB + t * DBS + RDT + 0);
      float4 B1 = *(const float4*)(dblB + t * DBS + RDT + 4);
      float4 B2 = *(const float4*)(dblB + t * DBS + RDT + 8);
      float4 B3 = *(const float4*)(dblB + t * DBS + RDT + 12);
      float acc = db;
      acc = fmaf(L0.x, w12[0], acc); acc = fmaf(L0.y, w12[1], acc);
      acc = fmaf(L0.z, w12[2], acc); acc = fmaf(L0.w, w12[3], acc);
      acc = fmaf(L1.x, w12[4], acc); acc = fmaf(L1.y, w12[5], acc);
      acc = fmaf(L1.z, w12[6], acc); acc = fmaf(L1.w, w12[7], acc);
      acc = fmaf(L2.x, w12[8], acc); acc = fmaf(L2.y, w12[9], acc);
      acc = fmaf(L2.z, w12[10], acc); acc = fmaf(L2.w, w12[11], acc);
      float dtv = (acc > 15.f) ? acc : __logf(1.f + __expf(acc));
      dtp16[(size_t)t * DI] = f2h(dtv);
      float uv  = bf2f(up[(size_t)t * DI]);
      float q = dtv * uv;
      S += dtv;
      float p1 = __expf(dtv * av0);
      float p2 = p1 * p1, p4 = p2 * p2, p8 = p4 * p4;
      f32x2 p2v = {p2, p2}, p4v = {p4, p4}, p8v = {p8, p8};
      f32x2 P0 = {p1, p2};
      f32x2 P1 = P0 * p2v;
      f32x2 P2 = P0 * p4v;
      f32x2 P3 = P1 * p4v;
      f32x2 P4 = P0 * p8v;
      f32x2 P5 = P1 * p8v;
      f32x2 P6 = P2 * p8v;
      f32x2 P7 = P3 * p8v;
      f32x2 qv = {q, q};
      h2[0] = P0 * h2[0] + qv * (f32x2){B0.x, B0.y};
      h2[1] = P1 * h2[1] + qv * (f32x2){B0.z, B0.w};
      h2[2] = P2 * h2[2] + qv * (f32x2){B1.x, B1.y};
      h2[3] = P3 * h2[3] + qv * (f32x2){B1.z, B1.w};
      h2[4] = P4 * h2[4] + qv * (f32x2){B2.x, B2.y};
      h2[5] = P5 * h2[5] + qv * (f32x2){B2.z, B2.w};
      h2[6] = P6 * h2[6] + qv * (f32x2){B3.x, B3.y};
      h2[7] = P7 * h2[7] + qv * (f32x2){B3.z, B3.w};
    }
    #pragma unroll
    for (int j = 0; j < 8; j += 2)
      *(float4*)(hend + o + j * 2) =
          make_float4(h2[j].x, h2[j].y, h2[j + 1].x, h2[j + 1].y);
  } else {
    float h[NST];
    #pragma unroll
    for (int j = 0; j < NST; j++) h[j] = 0.f;
    for (int t = 0; t < CLEN; t++) {
      float acc = db;
      #pragma unroll
      for (int rr = 0; rr < 12; rr++) acc = fmaf(dblB[t * DBS + rr], w12[rr], acc);
      float dtv = (acc > 15.f) ? acc : __logf(1.f + __expf(acc));
      dtp16[(size_t)t * DI] = f2h(dtv);
      float uv  = bf2f(up[(size_t)t * DI]);
      float q = dtv * uv;
      S += dtv;
      #pragma unroll
      for (int j = 0; j < NST; j++)
        h[j] = __expf(dtv * av_[j]) * h[j] + q * dblB[t * DBS + RDT + j];
    }
    #pragma unroll
    for (int j = 0; j < NST; j++) hend[o + j] = h[j];
  }
  Sbuf[(size_t)bd * NC + chunk] = S;
}

// ---------------------------------------------------------------------------
// Scan combine: decay products reconstructed as exp(S * av_s) from Sbuf.
__global__ __launch_bounds__(256) void scan_combine(
    float* __restrict__ hend, const float* __restrict__ Sbuf,
    const float* __restrict__ A_log) {
  __shared__ float sP[16][16], sH[16][16];
  int bd = blockIdx.x;
  int d = bd % DI;
  int s = threadIdx.x & 15, g = threadIdx.x >> 4;
  float av = -expf(A_log[d * NST + s]);
  size_t baseS = (size_t)bd * NC + g * NCH;
  size_t base = ((size_t)bd * NC + g * NCH) * NST + s;
  float Pl = 1.f, Hl = 0.f;
  #pragma unroll
  for (int k = 0; k < NCH; k++) {
    float p = __expf(Sbuf[baseS + k] * av);
    Hl = fmaf(p, Hl, hend[base + (size_t)k * NST]);
    Pl *= p;
  }
  sP[g][s] = Pl; sH[g][s] = Hl;
  __syncthreads();
  if (threadIdx.x < 16) {
    int ss = threadIdx.x;
    float c = 0.f;
    #pragma unroll
    for (int gg = 0; gg < 16; gg++) {
      float tmp = sH[gg][ss];
      float pp  = sP[gg][ss];
      sH[gg][ss] = c;
      c = fmaf(pp, c, tmp);
    }
  }
  __syncthreads();
  float c = sH[g][s];
  #pragma unroll
  for (int k = 0; k < NCH; k++) {
    size_t o = base + (size_t)k * NST;
    float p = __expf(Sbuf[baseS + k] * av);
    float he = hend[o];
    hend[o] = c;
    c = fmaf(p, c, he);
  }
}

// ---------------------------------------------------------------------------
// Scan phase 3: dt read as fp16; packed fp32 state update + y accumulation.
__global__ __launch_bounds__(384) void scan_phase3(
    const ushort_t* __restrict__ u_t, const float* __restrict__ dblT,
    const float* __restrict__ A_log, const ushort_t* __restrict__ dt16,
    const float* __restrict__ hin, const float* __restrict__ Dp,
    const ushort_t* __restrict__ xzT, ushort_t* __restrict__ ym_t) {
  int tid = threadIdx.x;
  int chunk = blockIdx.x, b = blockIdx.y;
  int t0 = chunk * CLEN;
  const float* dblB = dblT + ((size_t)b * LL + t0) * DBS;  // uniform base
  int d = tid;
  int bd = b * DI + d;
  float av0 = -expf(A_log[d * NST]);
  float av_[NST];
  bool ok = true;
  #pragma unroll
  for (int j = 0; j < NST; j++) {
    av_[j] = -expf(A_log[d * NST + j]);
    ok = ok && (fabsf(av_[j] - av0 * (float)(j + 1)) <= 1e-4f * fabsf(av_[j]));
  }
  const ushort_t* up = u_t + ((size_t)b * LL + t0) * DI + d;
  const ushort_t* zp = xzT + ((size_t)b * LL + t0) * XZS + DI + d;
  const ushort_t* dtp16 = dt16 + ((size_t)b * LL + t0) * DI + d;
  ushort_t* ymp = ym_t + ((size_t)b * LL + t0) * DI + d;

  const float* hi = hin + ((size_t)bd * NC + chunk) * NST;
  float Dv = Dp[d];

  if (__all(ok)) {
    f32x2 h2[8];
    #pragma unroll
    for (int j = 0; j < 8; j += 2) {
      float4 v = *(const float4*)(hi + j * 2);
      h2[j]     = (f32x2){v.x, v.y};
      h2[j + 1] = (f32x2){v.z, v.w};
    }
    #pragma unroll 2
    for (int t = 0; t < CLEN; t++) {
      float4 B0 = *(const float4*)(dblB + t * DBS + RDT + 0);
      float4 B1 = *(const float4*)(dblB + t * DBS + RDT + 4);
      float4 B2 = *(const float4*)(dblB + t * DBS + RDT + 8);
      float4 B3 = *(const float4*)(dblB + t * DBS + RDT + 12);
      float4 C0 = *(const float4*)(dblB + t * DBS + RDT + 16);
      float4 C1 = *(const float4*)(dblB + t * DBS + RDT + 20);
      float4 C2 = *(const float4*)(dblB + t * DBS + RDT + 24);
      float4 C3 = *(const float4*)(dblB + t * DBS + RDT + 28);
      float dtv = h2f(dtp16[(size_t)t * DI]);
      float uv  = bf2f(up[(size_t)t * DI]);
      float zv  = bf2f(zp[(size_t)t * XZS]);
      float q = dtv * uv;
      float p1 = __expf(dtv * av0);
      float p2 = p1 * p1, p4 = p2 * p2, p8 = p4 * p4;
      f32x2 p2v = {p2, p2}, p4v = {p4, p4}, p8v = {p8, p8};
      f32x2 P0 = {p1, p2};
      f32x2 P1 = P0 * p2v;
      f32x2 P2 = P0 * p4v;
      f32x2 P3 = P1 * p4v;
      f32x2 P4 = P0 * p8v;
      f32x2 P5 = P1 * p8v;
      f32x2 P6 = P2 * p8v;
      f32x2 P7 = P3 * p8v;
      f32x2 qv = {q, q};
      f32x2 ya, yb;
      h2[0] = P0 * h2[0] + qv * (f32x2){B0.x, B0.y};  ya = h2[0] * (f32x2){C0.x, C0.y};
      h2[1] = P1 * h2[1] + qv * (f32x2){B0.z, B0.w};  yb = h2[1] * (f32x2){C0.z, C0.w};
      h2[2] = P2 * h2[2] + qv * (f32x2){B1.x, B1.y};  ya = h2[2] * (f32x2){C1.x, C1.y} + ya;
      h2[3] = P3 * h2[3] + qv * (f32x2){B1.z, B1.w};  yb = h2[3] * (f32x2){C1.z, C1.w} + yb;
      h2[4] = P4 * h2[4] + qv * (f32x2){B2.x, B2.y};  ya = h2[4] * (f32x2){C2.x, C2.y} + ya;
      h2[5] = P5 * h2[5] + qv * (f32x2){B2.z, B2.w};  yb = h2[5] * (f32x2){C2.z, C2.w} + yb;
      h2[6] = P6 * h2[6] + qv * (f32x2){B3.x, B3.y};  ya = h2[6] * (f32x2){C3.x, C3.y} + ya;
      h2[7] = P7 * h2[7] + qv * (f32x2){B3.z, B3.w};  yb = h2[7] * (f32x2){C3.z, C3.w} + yb;
      float y = (ya.x + ya.y) + (yb.x + yb.y);
      float yv = (y + uv * Dv) * (zv / (1.f + __expf(-zv)));
      ymp[(size_t)t * DI] = f2bf(yv);
    }
  } else {
    float h[NST];
    #pragma unroll
    for (int j = 0; j < NST; j++) h[j] = hi[j];
    for (int t = 0; t < CLEN; t++) {
      float dtv = h2f(dtp16[(size_t)t * DI]);
      float uv  = bf2f(up[(size_t)t * DI]);
      float zv  = bf2f(zp[(size_t)t * XZS]);
      float q = dtv * uv;
      float y = 0.f;
      #pragma unroll
      for (int j = 0; j < NST; j++) {
        h[j] = __expf(dtv * av_[j]) * h[j] + q * dblB[t * DBS + RDT + j];
        y = fmaf(h[j], dblB[t * DBS + RDT + NST + j], y);
      }
      float yv = (y + uv * Dv) * (zv / (1.f + __expf(-zv)));
      ymp[(size_t)t * DI] = f2bf(yv);
    }
  }
}

// ---------------------------------------------------------------------------
extern "C" void kernel_launch(void* const* d_in, const int* in_sizes, int n_in,
                              void* d_out, int out_size, void* d_ws, size_t ws_size,
                              hipStream_t stream) {
  const float* x         = (const float*)d_in[0];
  const float* in_proj_w = (const float*)d_in[1];
  const float* conv_w    = (const float*)d_in[2];
  const float* conv_b    = (const float*)d_in[3];
  const float* x_proj_w  = (const float*)d_in[4];
  const float* dt_proj_w = (const float*)d_in[5];
  const float* dt_proj_b = (const float*)d_in[6];
  const float* A_log     = (const float*)d_in[7];
  const float* D_param   = (const float*)d_in[8];
  const float* out_proj_w= (const float*)d_in[9];
  const float* proj_w    = (const float*)d_in[10];
  const float* proj_b    = (const float*)d_in[11];
  float* out = (float*)d_out;

  // workspace layout (float units)
  float* w = (float*)d_ws;
  float*    mu     = w;                                   // 512
  float*    rstd   = w + 512;                             // 512
  float*    PW     = w + 1024;                            // 73,728
  ushort_t* PW_bf  = (ushort_t*)(w + 74752);              // 256x384 bf16 (49,152 f)
  ushort_t* ipw_bf = (ushort_t*)(w + 123904);             // 768x192 bf16 (73,728 f)
  ushort_t* xpw_bf = (ushort_t*)(w + 197632);             // 128x384 bf16 (24,576 f)
  ushort_t* xT     = (ushort_t*)(w + 222208);             // 6.29M bf16 (3,145,728 f)
  ushort_t* xzT    = (ushort_t*)(w + 3367936);            // 25.2M bf16 (12,582,912 f)
  ushort_t* u_t    = (ushort_t*)(w + 15950848);           // 12.6M bf16 (6,291,456 f)
  float*    dblT   = w + 22242304;                        // 2,097,152 f
  ushort_t* ym_t   = (ushort_t*)(w + 24339456);           // 12.6M bf16 (6,291,456 f)
  float*    hend   = w + 30630912;                        // 6,291,456 f
  float*    Sbuf   = w + 36922368;                        // 393,216 f
  ushort_t* dt16   = (ushort_t*)(w + 37315584);           // 12.6M fp16 (6,291,456 f)
  size_t need = 43607040;
  if (ws_size < need * sizeof(float)) return;

  norm_stats_kernel<<<dim3(BB * CM), dim3(256), 0, stream>>>(x, mu, rstd);
  fuse_proj_kernel<<<dim3((CM * DI + 255) / 256), dim3(256), 0, stream>>>(proj_w, out_proj_w, PW);
  cvt_weights_kernel<<<dim3((2 * DI * CM + 255) / 256), dim3(256), 0, stream>>>(
      in_proj_w, x_proj_w, PW, ipw_bf, xpw_bf, PW_bf);
  xt_norm_kernel<<<dim3(LL / 64, CM / 64, BB), dim3(256), 0, stream>>>(x, mu, rstd, xT);

  // GEMM1: xzT[b][t][768] = xT(BT) x in_proj_w   (M=768 => MT=6, K=192)
  gemm_lds<true, ushort_t><<<dim3(256 * 6), dim3(256), 0, stream>>>(
      ipw_bf, xT, xzT, CM, 768, 6, (long)LL * CM, (long)LL * XZS, XZS, nullptr);

  conv_silu_kernel<<<dim3(LL / CVT, BB), dim3(384), 0, stream>>>(xzT, conv_w, conv_b, u_t);

  // GEMM2: dblT[b][t][64] = u_t(BT) x x_proj_w(padded 128)  (Mreal=64, MT=1, K=384)
  gemm_lds<true, float><<<dim3(256 * 1), dim3(256), 0, stream>>>(
      xpw_bf, u_t, dblT, DI, 64, 1, (long)LL * DI, (long)LL * DBS, DBS, nullptr);

  scan_phase1<<<dim3(NC, BB), dim3(384), 0, stream>>>(
      u_t, dblT, A_log, dt_proj_w, dt_proj_b, hend, Sbuf, dt16);
  scan_combine<<<dim3(BB * DI), dim3(256), 0, stream>>>(hend, Sbuf, A_log);
  scan_phase3<<<dim3(NC, BB), dim3(384), 0, stream>>>(
      u_t, dblT, A_log, dt16, hend, D_param, xzT, ym_t);

  // GEMM3: out[b][192][L] = PW(padded 256) x ym_t(BT) + proj_b  (Mreal=192, MT=2, K=384)
  gemm_lds<false, float><<<dim3(256 * 2), dim3(256), 0, stream>>>(
      PW_bf, ym_t, out, DI, CM, 2, (long)LL * DI, (long)CM * LL, LL, proj_b);
}

// Round 11
// 189.092 us; speedup vs baseline: 1.4350x; 1.0141x over previous
//
#include <hip/hip_runtime.h>
#include <hip/hip_bf16.h>
#include <hip/hip_fp16.h>
#include <math.h>

// Problem constants
#define BB   2
#define CM   192        // D_MODEL
#define DI   384        // D_INNER
#define LL   16384      // D*H*W
#define NST  16         // D_STATE
#define RDT  12         // DT_RANK
#define XJ   44         // DT_RANK + 2*D_STATE
#define NC   512        // scan chunks
#define CLEN 32         // chunk length (NC*CLEN == LL)
#define NCH  (NC / 16)  // chunks per combine-thread
#define DBS  64         // dblT row stride (GEMM2 padded M)
#define XZS  768        // xzT row stride
#define CVT  32         // conv t-tile
#define BK   32         // GEMM k-tile

typedef __attribute__((ext_vector_type(8))) short bf16x8;
typedef __attribute__((ext_vector_type(4))) float f32x4;
typedef __attribute__((ext_vector_type(2))) float f32x2;
typedef unsigned short ushort_t;

static __device__ __forceinline__ ushort_t f2bf(float f) {
  __hip_bfloat16 h = __float2bfloat16(f);
  return *reinterpret_cast<ushort_t*>(&h);
}
static __device__ __forceinline__ float bf2f(ushort_t u) {
  __hip_bfloat16 h;
  *reinterpret_cast<ushort_t*>(&h) = u;
  return __bfloat162float(h);
}
static __device__ __forceinline__ ushort_t f2h(float f) {
  __half h = __float2half(f);
  return *reinterpret_cast<ushort_t*>(&h);
}
static __device__ __forceinline__ float h2f(ushort_t u) {
  __half h;
  *reinterpret_cast<ushort_t*>(&h) = u;
  return __half2float(h);
}

// ---------------------------------------------------------------------------
// PW = proj_w(192x192) @ out_proj_w(192x384)   (fp32, tiny)
__global__ __launch_bounds__(256) void fuse_proj_kernel(
    const float* __restrict__ pw, const float* __restrict__ ow, float* __restrict__ PW) {
  int idx = blockIdx.x * 256 + threadIdx.x;
  if (idx >= CM * DI) return;
  int o = idx / DI, d = idx % DI;
  float s = 0.f;
  #pragma unroll 4
  for (int c = 0; c < CM; c++) s += pw[o * CM + c] * ow[c * DI + d];
  PW[idx] = s;
}

// ---------------------------------------------------------------------------
// Weight conversions to bf16. Row-padding with zeros.
__global__ __launch_bounds__(256) void cvt_weights_kernel(
    const float* __restrict__ ipw, const float* __restrict__ xpw,
    const float* __restrict__ PW,
    ushort_t* __restrict__ ipw_bf, ushort_t* __restrict__ xpw_bf,
    ushort_t* __restrict__ PW_bf) {
  int i = blockIdx.x * 256 + threadIdx.x;
  if (i < 2 * DI * CM) ipw_bf[i] = f2bf(ipw[i]);
  if (i < 128 * DI) {
    int r = i / DI;
    xpw_bf[i] = (r < XJ) ? f2bf(xpw[i]) : (ushort_t)0;
  }
  if (i < 256 * DI) {
    int r = i / DI;
    PW_bf[i] = (r < CM) ? f2bf(PW[i]) : (ushort_t)0;
  }
}

// ---------------------------------------------------------------------------
// per-(b,c) mean / rstd over L
__global__ __launch_bounds__(256) void norm_stats_kernel(
    const float* __restrict__ x, float* __restrict__ mu, float* __restrict__ rstd) {
  int bc = blockIdx.x;
  const float* p = x + (size_t)bc * LL;
  float s = 0.f, ss = 0.f;
  for (int i = threadIdx.x * 4; i < LL; i += 256 * 4) {
    float4 v = *(const float4*)(p + i);
    s += v.x + v.y + v.z + v.w;
    ss += v.x * v.x + v.y * v.y + v.z * v.z + v.w * v.w;
  }
  for (int o = 32; o > 0; o >>= 1) {
    s += __shfl_down(s, o, 64);
    ss += __shfl_down(ss, o, 64);
  }
  __shared__ float sb[4], ssb[4];
  int wid = threadIdx.x >> 6;
  if ((threadIdx.x & 63) == 0) { sb[wid] = s; ssb[wid] = ss; }
  __syncthreads();
  if (threadIdx.x == 0) {
    s = sb[0] + sb[1] + sb[2] + sb[3];
    ss = ssb[0] + ssb[1] + ssb[2] + ssb[3];
    float m = s * (1.f / LL);
    float var = ss * (1.f / LL) - m * m;
    mu[bc] = m;
    rstd[bc] = 1.f / sqrtf(var + 1e-5f);
  }
}

// ---------------------------------------------------------------------------
// xT[b][t][c] bf16 = normalized x (LDS 64x64 transpose tile)
__global__ __launch_bounds__(256) void xt_norm_kernel(
    const float* __restrict__ x, const float* __restrict__ mu,
    const float* __restrict__ rstd, ushort_t* __restrict__ xT) {
  __shared__ ushort_t T[64][72];
  int t0 = blockIdx.x * 64, c0 = blockIdx.y * 64, b = blockIdx.z;
  int tid = threadIdx.x;
  int c = tid >> 2, tq = (tid & 3) * 16;
  int bc = b * CM + c0 + c;
  const float* xp = x + (size_t)bc * LL + t0 + tq;
  float m = mu[bc], rs = rstd[bc];
  #pragma unroll
  for (int j = 0; j < 16; j += 4) {
    float4 v = *(const float4*)(xp + j);
    T[c][tq + j + 0] = f2bf((v.x - m) * rs);
    T[c][tq + j + 1] = f2bf((v.y - m) * rs);
    T[c][tq + j + 2] = f2bf((v.z - m) * rs);
    T[c][tq + j + 3] = f2bf((v.w - m) * rs);
  }
  __syncthreads();
  int t = tid >> 2, cq = (tid & 3) * 16;
  unsigned int ob[8];
  #pragma unroll
  for (int j = 0; j < 8; j++)
    ob[j] = (unsigned int)T[cq + 2 * j][t] | ((unsigned int)T[cq + 2 * j + 1][t] << 16);
  ushort_t* op = xT + ((size_t)b * LL + t0 + t) * CM + c0 + cq;
  *(uint4*)(op)     = make_uint4(ob[0], ob[1], ob[2], ob[3]);
  *(uint4*)(op + 8) = make_uint4(ob[4], ob[5], ob[6], ob[7]);
}

// ---------------------------------------------------------------------------
// LDS-pipelined MFMA bf16 GEMM (BK=32 double-buffer, global_load_lds).
template <bool TOUT, typename OutT>
__global__ __launch_bounds__(256) void gemm_lds(
    const ushort_t* __restrict__ A, const ushort_t* __restrict__ BT,
    OutT* __restrict__ C, int K, int Mreal, int MT,
    long strideBT, long strideC, int ldc,
    const float* __restrict__ bias) {
  __shared__ ushort_t Asm[2][128 * BK];
  __shared__ ushort_t Bsm[2][128 * BK];

  int id = blockIdx.x;
  int per = MT * 8;
  int g = id / per, r = id % per;
  int nt = g * 8 + (r & 7);
  int mt = r >> 3;
  int b  = nt >> 7;
  long n0 = (long)(nt & 127) * 128;
  int m0 = mt * 128;

  int tid = threadIdx.x;
  int lane = tid & 63, wave = tid >> 6;
  const ushort_t* Bbase = BT + (size_t)b * strideBT;

  int srow0 = wave * 32 + (lane >> 2);
  int sk = (lane & 3) * 8;

  f32x4 acc[4][4];
  #pragma unroll
  for (int mi = 0; mi < 4; mi++)
    #pragma unroll
    for (int ni = 0; ni < 4; ni++) acc[mi][ni] = (f32x4){0.f, 0.f, 0.f, 0.f};

  int mh = wave & 1, nh = wave >> 1;
  int fr = lane & 15, fk = (lane >> 4) * 8;

  int nsteps = K / BK;
  {
    const ushort_t* As0 = A + (size_t)(m0 + srow0) * K + sk;
    const ushort_t* Bs0 = Bbase + (size_t)(n0 + srow0) * K + sk;
    __builtin_amdgcn_global_load_lds(As0, &Asm[0][wave * 1024], 16, 0, 0);
    __builtin_amdgcn_global_load_lds(As0 + (size_t)16 * K, &Asm[0][wave * 1024 + 512], 16, 0, 0);
    __builtin_amdgcn_global_load_lds(Bs0, &Bsm[0][wave * 1024], 16, 0, 0);
    __builtin_amdgcn_global_load_lds(Bs0 + (size_t)16 * K, &Bsm[0][wave * 1024 + 512], 16, 0, 0);
  }
  __syncthreads();
  int cur = 0;
  for (int s = 0; s < nsteps; s++) {
    if (s + 1 < nsteps) {
      int k0 = (s + 1) * BK;
      const ushort_t* As0 = A + (size_t)(m0 + srow0) * K + k0 + sk;
      const ushort_t* Bs0 = Bbase + (size_t)(n0 + srow0) * K + k0 + sk;
      __builtin_amdgcn_global_load_lds(As0, &Asm[cur ^ 1][wave * 1024], 16, 0, 0);
      __builtin_amdgcn_global_load_lds(As0 + (size_t)16 * K, &Asm[cur ^ 1][wave * 1024 + 512], 16, 0, 0);
      __builtin_amdgcn_global_load_lds(Bs0, &Bsm[cur ^ 1][wave * 1024], 16, 0, 0);
      __builtin_amdgcn_global_load_lds(Bs0 + (size_t)16 * K, &Bsm[cur ^ 1][wave * 1024 + 512], 16, 0, 0);
    }
    bf16x8 fa[4], fb[4];
    #pragma unroll
    for (int mi = 0; mi < 4; mi++)
      fa[mi] = *(const bf16x8*)&Asm[cur][(mh * 64 + mi * 16 + fr) * BK + fk];
    #pragma unroll
    for (int ni = 0; ni < 4; ni++)
      fb[ni] = *(const bf16x8*)&Bsm[cur][(nh * 64 + ni * 16 + fr) * BK + fk];
    #pragma unroll
    for (int mi = 0; mi < 4; mi++)
      #pragma unroll
      for (int ni = 0; ni < 4; ni++) {
        if constexpr (TOUT)
          acc[mi][ni] = __builtin_amdgcn_mfma_f32_16x16x32_bf16(fb[ni], fa[mi], acc[mi][ni], 0, 0, 0);
        else
          acc[mi][ni] = __builtin_amdgcn_mfma_f32_16x16x32_bf16(fa[mi], fb[ni], acc[mi][ni], 0, 0, 0);
      }
    __syncthreads();
    cur ^= 1;
  }

  int cq = (lane >> 4) * 4;
  if constexpr (TOUT) {
    #pragma unroll
    for (int ni = 0; ni < 4; ni++)
      #pragma unroll
      for (int rg = 0; rg < 4; rg++) {
        long n = n0 + nh * 64 + ni * 16 + cq + rg;
        OutT* cp = C + (size_t)b * strideC + n * ldc + m0 + mh * 64 + fr;
        #pragma unroll
        for (int mi = 0; mi < 4; mi++) {
          int mrow = m0 + mh * 64 + mi * 16 + fr;
          if (mrow < Mreal) {
            float v = acc[mi][ni][rg];
            if constexpr (sizeof(OutT) == 2) cp[mi * 16] = f2bf(v);
            else                             cp[mi * 16] = v;
          }
        }
      }
  } else {
    #pragma unroll
    for (int mi = 0; mi < 4; mi++)
      #pragma unroll
      for (int rg = 0; rg < 4; rg++) {
        int m = m0 + mh * 64 + mi * 16 + cq + rg;
        if (m < Mreal) {
          float bv = bias ? bias[m] : 0.f;
          OutT* cp = C + (size_t)b * strideC + (size_t)m * ldc + n0 + nh * 64 + fr;
          #pragma unroll
          for (int ni = 0; ni < 4; ni++)
            cp[ni * 16] = acc[mi][ni][rg] + bv;
        }
      }
  }
}

// ---------------------------------------------------------------------------
// Conv: causal depthwise k=4 + bias + SiLU.
__global__ __launch_bounds__(384) void conv_silu_kernel(
    const ushort_t* __restrict__ xzT, const float* __restrict__ conv_w,
    const float* __restrict__ conv_b, ushort_t* __restrict__ u_t) {
  __shared__ ushort_t Us[CVT + 3][DI];
  int t0 = blockIdx.x * CVT;
  int b = blockIdx.y;
  int tid = threadIdx.x;
  #pragma unroll
  for (int r = 0; r < CVT + 3; r++) {
    int t = t0 - 3 + r;
    Us[r][tid] = (t >= 0) ? xzT[((size_t)b * LL + t) * XZS + tid] : (ushort_t)0;
  }
  float w0 = conv_w[tid * 4 + 0], w1 = conv_w[tid * 4 + 1];
  float w2 = conv_w[tid * 4 + 2], w3 = conv_w[tid * 4 + 3];
  float cb = conv_b[tid];
  __syncthreads();
  ushort_t* up = u_t + ((size_t)b * LL + t0) * DI + tid;
  float xm3 = bf2f(Us[0][tid]);
  float xm2 = bf2f(Us[1][tid]);
  float xm1 = bf2f(Us[2][tid]);
  #pragma unroll
  for (int t = 0; t < CVT; t++) {
    float xc = bf2f(Us[t + 3][tid]);
    float a = cb + w3 * xc + w2 * xm1 + w1 * xm2 + w0 * xm3;
    float sv = a / (1.f + __expf(-a));
    up[(size_t)t * DI] = f2bf(sv);
    xm3 = xm2; xm2 = xm1; xm1 = xc;
  }
}

// ---------------------------------------------------------------------------
// Scan phase 1 (dt fused, packed fp32 state update).
// Block = 128 threads (2 waves) covering d in [d0, d0+128); grid (NC, 3, BB).
__global__ __launch_bounds__(128) void scan_phase1(
    const ushort_t* __restrict__ u_t, const float* __restrict__ dblT,
    const float* __restrict__ A_log,
    const float* __restrict__ dtw, const float* __restrict__ dtb,
    float* __restrict__ hend, float* __restrict__ Sbuf,
    ushort_t* __restrict__ dt16) {
  int chunk = blockIdx.x, b = blockIdx.z;
  int d = blockIdx.y * 128 + threadIdx.x;
  int t0 = chunk * CLEN;
  const float* dblB = dblT + ((size_t)b * LL + t0) * DBS;  // uniform base
  int bd = b * DI + d;
  float av0 = -expf(A_log[d * NST]);
  float av_[NST];
  bool ok = true;
  #pragma unroll
  for (int j = 0; j < NST; j++) {
    av_[j] = -expf(A_log[d * NST + j]);
    ok = ok && (fabsf(av_[j] - av0 * (float)(j + 1)) <= 1e-4f * fabsf(av_[j]));
  }
  float w12[12];
  #pragma unroll
  for (int rr = 0; rr < 12; rr += 4)
    *(float4*)(w12 + rr) = *(const float4*)(dtw + d * 12 + rr);
  float db = dtb[d];
  const ushort_t* up = u_t + ((size_t)b * LL + t0) * DI + d;
  ushort_t* dtp16 = dt16 + ((size_t)b * LL + t0) * DI + d;
  float S = 0.f;

  size_t o = ((size_t)bd * NC + chunk) * NST;
  if (__all(ok)) {
    f32x2 h2[8];
    #pragma unroll
    for (int j = 0; j < 8; j++) h2[j] = (f32x2){0.f, 0.f};
    #pragma unroll 4
    for (int t = 0; t < CLEN; t++) {
      float4 L0 = *(const float4*)(dblB + t * DBS + 0);
      float4 L1 = *(const float4*)(dblB + t * DBS + 4);
      float4 L2 = *(const float4*)(dblB + t * DBS + 8);
      float4 B0 = *(const float4*)(dblB + t * DBS + RDT + 0);
      float4 B1 = *(const float4*)(dblB + t * DBS + RDT + 4);
      float4 B2 = *(const float4*)(dblB + t * DBS + RDT + 8);
      float4 B3 = *(const float4*)(dblB + t * DBS + RDT + 12);
      float acc = db;
      acc = fmaf(L0.x, w12[0], acc); acc = fmaf(L0.y, w12[1], acc);
      acc = fmaf(L0.z, w12[2], acc); acc = fmaf(L0.w, w12[3], acc);
      acc = fmaf(L1.x, w12[4], acc); acc = fmaf(L1.y, w12[5], acc);
      acc = fmaf(L1.z, w12[6], acc); acc = fmaf(L1.w, w12[7], acc);
      acc = fmaf(L2.x, w12[8], acc); acc = fmaf(L2.y, w12[9], acc);
      acc = fmaf(L2.z, w12[10], acc); acc = fmaf(L2.w, w12[11], acc);
      float dtv = (acc > 15.f) ? acc : __logf(1.f + __expf(acc));
      dtp16[(size_t)t * DI] = f2h(dtv);
      float uv  = bf2f(up[(size_t)t * DI]);
      float q = dtv * uv;
      S += dtv;
      float p1 = __expf(dtv * av0);
      float p2 = p1 * p1, p4 = p2 * p2, p8 = p4 * p4;
      f32x2 p2v = {p2, p2}, p4v = {p4, p4}, p8v = {p8, p8};
      f32x2 P0 = {p1, p2};
      f32x2 P1 = P0 * p2v;
      f32x2 P2 = P0 * p4v;
      f32x2 P3 = P1 * p4v;
      f32x2 P4 = P0 * p8v;
      f32x2 P5 = P1 * p8v;
      f32x2 P6 = P2 * p8v;
      f32x2 P7 = P3 * p8v;
      f32x2 qv = {q, q};
      h2[0] = P0 * h2[0] + qv * (f32x2){B0.x, B0.y};
      h2[1] = P1 * h2[1] + qv * (f32x2){B0.z, B0.w};
      h2[2] = P2 * h2[2] + qv * (f32x2){B1.x, B1.y};
      h2[3] = P3 * h2[3] + qv * (f32x2){B1.z, B1.w};
      h2[4] = P4 * h2[4] + qv * (f32x2){B2.x, B2.y};
      h2[5] = P5 * h2[5] + qv * (f32x2){B2.z, B2.w};
      h2[6] = P6 * h2[6] + qv * (f32x2){B3.x, B3.y};
      h2[7] = P7 * h2[7] + qv * (f32x2){B3.z, B3.w};
    }
    #pragma unroll
    for (int j = 0; j < 8; j += 2)
      *(float4*)(hend + o + j * 2) =
          make_float4(h2[j].x, h2[j].y, h2[j + 1].x, h2[j + 1].y);
  } else {
    float h[NST];
    #pragma unroll
    for (int j = 0; j < NST; j++) h[j] = 0.f;
    for (int t = 0; t < CLEN; t++) {
      float acc = db;
      #pragma unroll
      for (int rr = 0; rr < 12; rr++) acc = fmaf(dblB[t * DBS + rr], w12[rr], acc);
      float dtv = (acc > 15.f) ? acc : __logf(1.f + __expf(acc));
      dtp16[(size_t)t * DI] = f2h(dtv);
      float uv  = bf2f(up[(size_t)t * DI]);
      float q = dtv * uv;
      S += dtv;
      #pragma unroll
      for (int j = 0; j < NST; j++)
        h[j] = __expf(dtv * av_[j]) * h[j] + q * dblB[t * DBS + RDT + j];
    }
    #pragma unroll
    for (int j = 0; j < NST; j++) hend[o + j] = h[j];
  }
  Sbuf[(size_t)bd * NC + chunk] = S;
}

// ---------------------------------------------------------------------------
// Scan combine: decay products reconstructed as exp(S * av_s) from Sbuf.
__global__ __launch_bounds__(256) void scan_combine(
    float* __restrict__ hend, const float* __restrict__ Sbuf,
    const float* __restrict__ A_log) {
  __shared__ float sP[16][16], sH[16][16];
  int bd = blockIdx.x;
  int d = bd % DI;
  int s = threadIdx.x & 15, g = threadIdx.x >> 4;
  float av = -expf(A_log[d * NST + s]);
  size_t baseS = (size_t)bd * NC + g * NCH;
  size_t base = ((size_t)bd * NC + g * NCH) * NST + s;
  float Pl = 1.f, Hl = 0.f;
  #pragma unroll
  for (int k = 0; k < NCH; k++) {
    float p = __expf(Sbuf[baseS + k] * av);
    Hl = fmaf(p, Hl, hend[base + (size_t)k * NST]);
    Pl *= p;
  }
  sP[g][s] = Pl; sH[g][s] = Hl;
  __syncthreads();
  if (threadIdx.x < 16) {
    int ss = threadIdx.x;
    float c = 0.f;
    #pragma unroll
    for (int gg = 0; gg < 16; gg++) {
      float tmp = sH[gg][ss];
      float pp  = sP[gg][ss];
      sH[gg][ss] = c;
      c = fmaf(pp, c, tmp);
    }
  }
  __syncthreads();
  float c = sH[g][s];
  #pragma unroll
  for (int k = 0; k < NCH; k++) {
    size_t o = base + (size_t)k * NST;
    float p = __expf(Sbuf[baseS + k] * av);
    float he = hend[o];
    hend[o] = c;
    c = fmaf(p, c, he);
  }
}

// ---------------------------------------------------------------------------
// Scan phase 3: dt read as fp16; packed fp32 state update + y accumulation.
// Block = 128 threads (2 waves); grid (NC, 3, BB).
__global__ __launch_bounds__(128) void scan_phase3(
    const ushort_t* __restrict__ u_t, const float* __restrict__ dblT,
    const float* __restrict__ A_log, const ushort_t* __restrict__ dt16,
    const float* __restrict__ hin, const float* __restrict__ Dp,
    const ushort_t* __restrict__ xzT, ushort_t* __restrict__ ym_t) {
  int chunk = blockIdx.x, b = blockIdx.z;
  int d = blockIdx.y * 128 + threadIdx.x;
  int t0 = chunk * CLEN;
  const float* dblB = dblT + ((size_t)b * LL + t0) * DBS;  // uniform base
  int bd = b * DI + d;
  float av0 = -expf(A_log[d * NST]);
  float av_[NST];
  bool ok = true;
  #pragma unroll
  for (int j = 0; j < NST; j++) {
    av_[j] = -expf(A_log[d * NST + j]);
    ok = ok && (fabsf(av_[j] - av0 * (float)(j + 1)) <= 1e-4f * fabsf(av_[j]));
  }
  const ushort_t* up = u_t + ((size_t)b * LL + t0) * DI + d;
  const ushort_t* zp = xzT + ((size_t)b * LL + t0) * XZS + DI + d;
  const ushort_t* dtp16 = dt16 + ((size_t)b * LL + t0) * DI + d;
  ushort_t* ymp = ym_t + ((size_t)b * LL + t0) * DI + d;

  const float* hi = hin + ((size_t)bd * NC + chunk) * NST;
  float Dv = Dp[d];

  if (__all(ok)) {
    f32x2 h2[8];
    #pragma unroll
    for (int j = 0; j < 8; j += 2) {
      float4 v = *(const float4*)(hi + j * 2);
      h2[j]     = (f32x2){v.x, v.y};
      h2[j + 1] = (f32x2){v.z, v.w};
    }
    #pragma unroll 4
    for (int t = 0; t < CLEN; t++) {
      float4 B0 = *(const float4*)(dblB + t * DBS + RDT + 0);
      float4 B1 = *(const float4*)(dblB + t * DBS + RDT + 4);
      float4 B2 = *(const float4*)(dblB + t * DBS + RDT + 8);
      float4 B3 = *(const float4*)(dblB + t * DBS + RDT + 12);
      float4 C0 = *(const float4*)(dblB + t * DBS + RDT + 16);
      float4 C1 = *(const float4*)(dblB + t * DBS + RDT + 20);
      float4 C2 = *(const float4*)(dblB + t * DBS + RDT + 24);
      float4 C3 = *(const float4*)(dblB + t * DBS + RDT + 28);
      float dtv = h2f(dtp16[(size_t)t * DI]);
      float uv  = bf2f(up[(size_t)t * DI]);
      float zv  = bf2f(zp[(size_t)t * XZS]);
      float q = dtv * uv;
      float p1 = __expf(dtv * av0);
      float p2 = p1 * p1, p4 = p2 * p2, p8 = p4 * p4;
      f32x2 p2v = {p2, p2}, p4v = {p4, p4}, p8v = {p8, p8};
      f32x2 P0 = {p1, p2};
      f32x2 P1 = P0 * p2v;
      f32x2 P2 = P0 * p4v;
      f32x2 P3 = P1 * p4v;
      f32x2 P4 = P0 * p8v;
      f32x2 P5 = P1 * p8v;
      f32x2 P6 = P2 * p8v;
      f32x2 P7 = P3 * p8v;
      f32x2 qv = {q, q};
      f32x2 ya, yb;
      h2[0] = P0 * h2[0] + qv * (f32x2){B0.x, B0.y};  ya = h2[0] * (f32x2){C0.x, C0.y};
      h2[1] = P1 * h2[1] + qv * (f32x2){B0.z, B0.w};  yb = h2[1] * (f32x2){C0.z, C0.w};
      h2[2] = P2 * h2[2] + qv * (f32x2){B1.x, B1.y};  ya = h2[2] * (f32x2){C1.x, C1.y} + ya;
      h2[3] = P3 * h2[3] + qv * (f32x2){B1.z, B1.w};  yb = h2[3] * (f32x2){C1.z, C1.w} + yb;
      h2[4] = P4 * h2[4] + qv * (f32x2){B2.x, B2.y};  ya = h2[4] * (f32x2){C2.x, C2.y} + ya;
      h2[5] = P5 * h2[5] + qv * (f32x2){B2.z, B2.w};  yb = h2[5] * (f32x2){C2.z, C2.w} + yb;
      h2[6] = P6 * h2[6] + qv * (f32x2){B3.x, B3.y};  ya = h2[6] * (f32x2){C3.x, C3.y} + ya;
      h2[7] = P7 * h2[7] + qv * (f32x2){B3.z, B3.w};  yb = h2[7] * (f32x2){C3.z, C3.w} + yb;
      float y = (ya.x + ya.y) + (yb.x + yb.y);
      float yv = (y + uv * Dv) * (zv / (1.f + __expf(-zv)));
      ymp[(size_t)t * DI] = f2bf(yv);
    }
  } else {
    float h[NST];
    #pragma unroll
    for (int j = 0; j < NST; j++) h[j] = hi[j];
    for (int t = 0; t < CLEN; t++) {
      float dtv = h2f(dtp16[(size_t)t * DI]);
      float uv  = bf2f(up[(size_t)t * DI]);
      float zv  = bf2f(zp[(size_t)t * XZS]);
      float q = dtv * uv;
      float y = 0.f;
      #pragma unroll
      for (int j = 0; j < NST; j++) {
        h[j] = __expf(dtv * av_[j]) * h[j] + q * dblB[t * DBS + RDT + j];
        y = fmaf(h[j], dblB[t * DBS + RDT + NST + j], y);
      }
      float yv = (y + uv * Dv) * (zv / (1.f + __expf(-zv)));
      ymp[(size_t)t * DI] = f2bf(yv);
    }
  }
}

// ---------------------------------------------------------------------------
extern "C" void kernel_launch(void* const* d_in, const int* in_sizes, int n_in,
                              void* d_out, int out_size, void* d_ws, size_t ws_size,
                              hipStream_t stream) {
  const float* x         = (const float*)d_in[0];
  const float* in_proj_w = (const float*)d_in[1];
  const float* conv_w    = (const float*)d_in[2];
  const float* conv_b    = (const float*)d_in[3];
  const float* x_proj_w  = (const float*)d_in[4];
  const float* dt_proj_w = (const float*)d_in[5];
  const float* dt_proj_b = (const float*)d_in[6];
  const float* A_log     = (const float*)d_in[7];
  const float* D_param   = (const float*)d_in[8];
  const float* out_proj_w= (const float*)d_in[9];
  const float* proj_w    = (const float*)d_in[10];
  const float* proj_b    = (const float*)d_in[11];
  float* out = (float*)d_out;

  // workspace layout (float units)
  float* w = (float*)d_ws;
  float*    mu     = w;                                   // 512
  float*    rstd   = w + 512;                             // 512
  float*    PW     = w + 1024;                            // 73,728
  ushort_t* PW_bf  = (ushort_t*)(w + 74752);              // 256x384 bf16 (49,152 f)
  ushort_t* ipw_bf = (ushort_t*)(w + 123904);             // 768x192 bf16 (73,728 f)
  ushort_t* xpw_bf = (ushort_t*)(w + 197632);             // 128x384 bf16 (24,576 f)
  ushort_t* xT     = (ushort_t*)(w + 222208);             // 6.29M bf16 (3,145,728 f)
  ushort_t* xzT    = (ushort_t*)(w + 3367936);            // 25.2M bf16 (12,582,912 f)
  ushort_t* u_t    = (ushort_t*)(w + 15950848);           // 12.6M bf16 (6,291,456 f)
  float*    dblT   = w + 22242304;                        // 2,097,152 f
  ushort_t* ym_t   = (ushort_t*)(w + 24339456);           // 12.6M bf16 (6,291,456 f)
  float*    hend   = w + 30630912;                        // 6,291,456 f
  float*    Sbuf   = w + 36922368;                        // 393,216 f
  ushort_t* dt16   = (ushort_t*)(w + 37315584);           // 12.6M fp16 (6,291,456 f)
  size_t need = 43607040;
  if (ws_size < need * sizeof(float)) return;

  norm_stats_kernel<<<dim3(BB * CM), dim3(256), 0, stream>>>(x, mu, rstd);
  fuse_proj_kernel<<<dim3((CM * DI + 255) / 256), dim3(256), 0, stream>>>(proj_w, out_proj_w, PW);
  cvt_weights_kernel<<<dim3((2 * DI * CM + 255) / 256), dim3(256), 0, stream>>>(
      in_proj_w, x_proj_w, PW, ipw_bf, xpw_bf, PW_bf);
  xt_norm_kernel<<<dim3(LL / 64, CM / 64, BB), dim3(256), 0, stream>>>(x, mu, rstd, xT);

  // GEMM1: xzT[b][t][768] = xT(BT) x in_proj_w   (M=768 => MT=6, K=192)
  gemm_lds<true, ushort_t><<<dim3(256 * 6), dim3(256), 0, stream>>>(
      ipw_bf, xT, xzT, CM, 768, 6, (long)LL * CM, (long)LL * XZS, XZS, nullptr);

  conv_silu_kernel<<<dim3(LL / CVT, BB), dim3(384), 0, stream>>>(xzT, conv_w, conv_b, u_t);

  // GEMM2: dblT[b][t][64] = u_t(BT) x x_proj_w(padded 128)  (Mreal=64, MT=1, K=384)
  gemm_lds<true, float><<<dim3(256 * 1), dim3(256), 0, stream>>>(
      xpw_bf, u_t, dblT, DI, 64, 1, (long)LL * DI, (long)LL * DBS, DBS, nullptr);

  scan_phase1<<<dim3(NC, 3, BB), dim3(128), 0, stream>>>(
      u_t, dblT, A_log, dt_proj_w, dt_proj_b, hend, Sbuf, dt16);
  scan_combine<<<dim3(BB * DI), dim3(256), 0, stream>>>(hend, Sbuf, A_log);
  scan_phase3<<<dim3(NC, 3, BB), dim3(128), 0, stream>>>(
      u_t, dblT, A_log, dt16, hend, D_param, xzT, ym_t);

  // GEMM3: out[b][192][L] = PW(padded 256) x ym_t(BT) + proj_b  (Mreal=192, MT=2, K=384)
  gemm_lds<false, float><<<dim3(256 * 2), dim3(256), 0, stream>>>(
      PW_bf, ym_t, out, DI, CM, 2, (long)LL * DI, (long)CM * LL, LL, proj_b);
}